// Round 1
// baseline (1485.861 us; speedup 1.0000x reference)
//
#include <hip/hip_runtime.h>
#include <hip/hip_bf16.h>
#include <math.h>

#define BB 4
#define CC 64
#define HH 128
#define WW 128
#define HW (HH*WW)          // 16384
#define NPIX (BB*HW)        // 65536

// ---------------------------------------------------------------------------
// Kernel 1: NCHW -> channels-last transpose for x and inter.
// grid 1024 blocks (512 for x, 512 for inter), 256 threads.
// LDS tile [64][129] (pad +1 -> conflict-free transpose).
// ---------------------------------------------------------------------------
__global__ __launch_bounds__(256) void k_transpose(
    const float* __restrict__ x, const float* __restrict__ inter,
    float* __restrict__ x_cl, float* __restrict__ inter_cl) {
  __shared__ float tile[64 * 129];
  int blk = blockIdx.x;
  int bh  = blk & 511;
  int b   = bh >> 7, h = bh & 127;
  const float* src = (blk < 512) ? x : inter;
  float*       dst = (blk < 512) ? x_cl : inter_cl;
  const float* sp = src + (size_t)(b * CC) * HW + h * WW;
  for (int i = threadIdx.x; i < 64 * 128; i += 256) {
    int c = i >> 7, w = i & 127;
    tile[c * 129 + w] = sp[(size_t)c * HW + w];
  }
  __syncthreads();
  float* dp = dst + ((size_t)b * HW + h * WW) * 64;
  for (int i = threadIdx.x; i < 64 * 128; i += 256) {
    int w = i >> 6, c = i & 63;
    dp[w * 64 + c] = tile[c * 129 + w];
  }
}

// ---------------------------------------------------------------------------
// Kernel 2: transpose w_dcn [o][c][k] -> wdT [o][k][c]  (36864 elements)
// ---------------------------------------------------------------------------
__global__ void k_wdt(const float* __restrict__ w_dcn, float* __restrict__ wdT) {
  int i = blockIdx.x * 256 + threadIdx.x;
  if (i < 64 * 64 * 9) {
    int o = i / 576, rem = i % 576, k = rem >> 6, c = rem & 63;
    wdT[i] = w_dcn[(o * 64 + c) * 9 + k];
  }
}

// ---------------------------------------------------------------------------
// Kernel 3: offset conv. 3x3 conv, 128 in-ch (x ++ inter), 27 out-ch.
// One block = 16x16 pixel tile, 256 threads, loop over 128 channels.
// Input tile (18x18 w/ halo) staged in LDS; weights are wave-uniform ->
// compiler scalarizes to s_load (broadcast via SGPR, keeps LDS pipe free).
// Output layout: om[j][NPIX] planes, j in 0..26; mask planes pre-sigmoided.
// ---------------------------------------------------------------------------
__global__ __launch_bounds__(256) void k_conv(
    const float* __restrict__ x, const float* __restrict__ inter,
    const float* __restrict__ w_off, const float* __restrict__ b_off,
    float* __restrict__ om) {
  __shared__ float tile[18 * 18];
  int blk = blockIdx.x;                       // 256 blocks: b(4) x 8 x 8 tiles
  int b  = blk >> 6;
  int h0 = ((blk >> 3) & 7) * 16;
  int w0 = (blk & 7) * 16;
  int ty = threadIdx.x >> 4, tx = threadIdx.x & 15;

  float acc[27];
#pragma unroll
  for (int o = 0; o < 27; ++o) acc[o] = 0.f;

  for (int c = 0; c < 128; ++c) {
    __syncthreads();
    const float* sp = (c < 64) ? (x + (size_t)(b * 64 + c) * HW)
                               : (inter + (size_t)(b * 64 + (c - 64)) * HW);
    for (int i = threadIdx.x; i < 324; i += 256) {
      int r = i / 18, cc = i % 18;
      int gy = h0 - 1 + r, gx = w0 - 1 + cc;
      float v = 0.f;
      if ((unsigned)gy < 128u && (unsigned)gx < 128u) v = sp[gy * WW + gx];
      tile[i] = v;
    }
    __syncthreads();
    float v[9];
#pragma unroll
    for (int r = 0; r < 3; ++r)
#pragma unroll
      for (int cc = 0; cc < 3; ++cc)
        v[r * 3 + cc] = tile[(ty + r) * 18 + tx + cc];
    const float* wrow = w_off + (size_t)c * 9;   // + o*128*9 + t
#pragma unroll
    for (int o = 0; o < 27; ++o) {
#pragma unroll
      for (int t = 0; t < 9; ++t)
        acc[o] += wrow[(size_t)o * 1152 + t] * v[t];
    }
  }

  int p = b * HW + (h0 + ty) * WW + (w0 + tx);
#pragma unroll
  for (int j = 0; j < 9; ++j) {
    om[(size_t)j * NPIX + p]       = acc[j] + b_off[j];
    om[(size_t)(9 + j) * NPIX + p] = acc[9 + j] + b_off[9 + j];
    float z = acc[18 + j] + b_off[18 + j];
    om[(size_t)(18 + j) * NPIX + p] = 1.f / (1.f + __expf(-z));
  }
}

// ---------------------------------------------------------------------------
// Kernel 4: SFT path.  out = x*(1+gamma) + beta  (dcn added by kernel 5).
// One block = 1 wave = 64 pixels; lane = pixel. LDS rows (pitch 65,
// bank = lane+c -> conflict-free) act as an indexed register file so the
// o-loops stay rolled (no icache blowup). Weights: uniform -> s_load.
// ---------------------------------------------------------------------------
__global__ __launch_bounds__(64) void k_sft(
    const float* __restrict__ x, const float* __restrict__ inter_cl,
    const float* __restrict__ wg1, const float* __restrict__ wg2,
    const float* __restrict__ wb1, const float* __restrict__ wb2,
    float* __restrict__ out) {
  __shared__ float vsh[64 * 65];
  __shared__ float tg[64 * 65];
  __shared__ float tb[64 * 65];
  int lane = threadIdx.x;
  int p0 = blockIdx.x * 64;

  for (int i = lane; i < 4096; i += 64)
    vsh[(i >> 6) * 65 + (i & 63)] = inter_cl[(size_t)p0 * 64 + i];
  __syncthreads();

  {
    float s[64];
#pragma unroll
    for (int c = 0; c < 64; ++c) s[c] = vsh[lane * 65 + c];
#pragma unroll 1
    for (int o = 0; o < 64; ++o) {
      float ag = 0.f, ab = 0.f;
#pragma unroll
      for (int c = 0; c < 64; ++c) {
        ag += wg1[o * 64 + c] * s[c];
        ab += wb1[o * 64 + c] * s[c];
      }
      tg[lane * 65 + o] = ag;
      tb[lane * 65 + o] = ab;
    }
  }

  float sg[64], sb[64];
#pragma unroll
  for (int c = 0; c < 64; ++c) {
    float a = tg[lane * 65 + c];
    sg[c] = a >= 0.f ? a : 0.1f * a;
    float d = tb[lane * 65 + c];
    sb[c] = d >= 0.f ? d : 0.1f * d;
  }

  int pg = p0 + lane;
  int b = pg >> 14, hw = pg & 16383;
#pragma unroll 1
  for (int o = 0; o < 64; ++o) {
    float g = 0.f, bt = 0.f;
#pragma unroll
    for (int c = 0; c < 64; ++c) {
      g  += wg2[o * 64 + c] * sg[c];
      bt += wb2[o * 64 + c] * sb[c];
    }
    size_t idx = (size_t)(b * 64 + o) * HW + hw;
    float xv = x[idx];
    out[idx] = xv + xv * g + bt;
  }
}

// ---------------------------------------------------------------------------
// Kernel 5: DCN. Block = 256 thr (4 waves) = 64 pixels.
// Loop over 3 k-chunks: phase1 gathers bilinear samples (lane=c, coalesced
// 256B from x_cl) into LDS samp[kk][p][65]; phase2: lane=pixel, wave w owns
// o in [16w,16w+16), weights via readfirstlane-forced s_load broadcast.
// Epilogue RMW-adds into out (coalesced: lanes = consecutive hw).
// ---------------------------------------------------------------------------
__global__ __launch_bounds__(256) void k_dcn(
    const float* __restrict__ x_cl, const float* __restrict__ om,
    const float* __restrict__ wdT, float* __restrict__ out) {
  __shared__ float samp[3 * 64 * 65];
  int tid = threadIdx.x;
  int wave = tid >> 6, lane = tid & 63;
  int pg0 = blockIdx.x * 64;
  int b = pg0 >> 14;
  int o_base = __builtin_amdgcn_readfirstlane(wave * 16);

  float acc[16];
#pragma unroll
  for (int i = 0; i < 16; ++i) acc[i] = 0.f;

  const float* bp = x_cl + (size_t)b * HW * 64;

  for (int k3 = 0; k3 < 3; ++k3) {
    __syncthreads();
    // phase 1: fill samples for k = 3*k3 .. 3*k3+2
    for (int pr = wave; pr < 192; pr += 4) {
      int kk = pr >> 6, p = pr & 63;
      int k = k3 * 3 + kk;
      int pg = pg0 + p;
      int hw = pg & 16383;
      int h = hw >> 7, w = hw & 127;
      float dy = om[(size_t)k * NPIX + pg];
      float dx = om[(size_t)(9 + k) * NPIX + pg];
      float m  = om[(size_t)(18 + k) * NPIX + pg];
      float py = (float)(h + (k / 3) - 1) + dy;
      float px = (float)(w + (k % 3) - 1) + dx;
      float y0f = floorf(py), x0f = floorf(px);
      float wy = py - y0f, wx = px - x0f;
      int y0 = (int)y0f, x0 = (int)x0f;
      int c = lane;
      float v00 = 0.f, v01 = 0.f, v10 = 0.f, v11 = 0.f;
      if ((unsigned)y0 < 128u) {
        if ((unsigned)x0 < 128u)       v00 = bp[(size_t)((y0 << 7) + x0) * 64 + c];
        if ((unsigned)(x0 + 1) < 128u) v01 = bp[(size_t)((y0 << 7) + x0 + 1) * 64 + c];
      }
      if ((unsigned)(y0 + 1) < 128u) {
        if ((unsigned)x0 < 128u)       v10 = bp[(size_t)(((y0 + 1) << 7) + x0) * 64 + c];
        if ((unsigned)(x0 + 1) < 128u) v11 = bp[(size_t)(((y0 + 1) << 7) + x0 + 1) * 64 + c];
      }
      float val = v00 * (1.f - wy) * (1.f - wx) + v01 * (1.f - wy) * wx +
                  v10 * wy * (1.f - wx) + v11 * wy * wx;
      samp[(kk * 64 + p) * 65 + c] = m * val;
    }
    __syncthreads();
    // phase 2: acc[oi] += sum_{kk,c} wdT[o][k][c] * samp[kk][lane][c]
    for (int kk = 0; kk < 3; ++kk) {
      int k = k3 * 3 + kk;
      const float* wbase = wdT + (size_t)k * 64;
      for (int c0 = 0; c0 < 64; c0 += 16) {
        float sreg[16];
#pragma unroll
        for (int j = 0; j < 16; ++j)
          sreg[j] = samp[(kk * 64 + lane) * 65 + c0 + j];
#pragma unroll
        for (int oi = 0; oi < 16; ++oi) {
          const float* wr = wbase + (size_t)(o_base + oi) * 576 + c0;
#pragma unroll
          for (int j = 0; j < 16; ++j) acc[oi] += wr[j] * sreg[j];
        }
      }
    }
  }

  int hw = (pg0 & 16383) + lane;
#pragma unroll
  for (int oi = 0; oi < 16; ++oi) {
    size_t idx = (size_t)(b * 64 + o_base + oi) * HW + hw;
    out[idx] += acc[oi];
  }
}

// ---------------------------------------------------------------------------
extern "C" void kernel_launch(void* const* d_in, const int* in_sizes, int n_in,
                              void* d_out, int out_size, void* d_ws, size_t ws_size,
                              hipStream_t stream) {
  const float* x     = (const float*)d_in[0];
  const float* inter = (const float*)d_in[1];
  const float* w_off = (const float*)d_in[2];
  const float* b_off = (const float*)d_in[3];
  const float* w_dcn = (const float*)d_in[4];
  const float* wg1   = (const float*)d_in[5];
  const float* wg2   = (const float*)d_in[6];
  const float* wb1   = (const float*)d_in[7];
  const float* wb2   = (const float*)d_in[8];
  float* out = (float*)d_out;

  float* ws       = (float*)d_ws;
  float* x_cl     = ws;                      // 4194304 floats
  float* inter_cl = ws + 4194304;            // 4194304 floats
  float* om       = ws + 8388608;            // 27*65536 = 1769472 floats
  float* wdT      = ws + 8388608 + 1769472;  // 36864 floats

  k_transpose<<<1024, 256, 0, stream>>>(x, inter, x_cl, inter_cl);
  k_wdt<<<144, 256, 0, stream>>>(w_dcn, wdT);
  k_conv<<<256, 256, 0, stream>>>(x, inter, w_off, b_off, om);
  k_sft<<<1024, 64, 0, stream>>>(x, inter_cl, wg1, wg2, wb1, wb2, out);
  k_dcn<<<1024, 256, 0, stream>>>(x_cl, om, wdT, out);
}

// Round 2
// 730.257 us; speedup vs baseline: 2.0347x; 2.0347x over previous
//
#include <hip/hip_runtime.h>
#include <hip/hip_bf16.h>
#include <math.h>

#define BB 4
#define CC 64
#define HH 128
#define WW 128
#define HW (HH*WW)          // 16384
#define NPIX (BB*HW)        // 65536

// ---------------------------------------------------------------------------
// SFT stage A: t1g = lrelu(Wg1 @ inter), t1b = lrelu(Wb1 @ inter).
// Block = 256 thr = 4 waves over the same 64 pixels; wave w owns rows
// [16w,16w+16). Pixel column (64 ch) loaded into 64 VGPRs (coalesced, all
// 64 loads in flight); weight rows are wave-uniform -> s_load broadcast.
// Two independent 64-deep FMA chains per row hide 4cy FMA latency at 2cy
// wave64 issue.
// ---------------------------------------------------------------------------
__global__ __launch_bounds__(256) void k_sftA(
    const float* __restrict__ inter,
    const float* __restrict__ wg1, const float* __restrict__ wb1,
    float* __restrict__ t1g, float* __restrict__ t1b) {
  int tid = threadIdx.x;
  int lane = tid & 63;
  int o_base = __builtin_amdgcn_readfirstlane((tid >> 6) * 16);
  int pg = blockIdx.x * 64 + lane;
  int b = pg >> 14, hw = pg & 16383;
  const float* ip = inter + (size_t)(b * 64) * HW + hw;

  float xv[64];
#pragma unroll
  for (int c = 0; c < 64; ++c) xv[c] = ip[(size_t)c * HW];

#pragma unroll 1
  for (int oi = 0; oi < 16; ++oi) {
    int o = o_base + oi;
    const float* rg = wg1 + (size_t)o * 64;
    const float* rb = wb1 + (size_t)o * 64;
    float ag = 0.f, ab = 0.f;
#pragma unroll
    for (int c = 0; c < 64; ++c) {
      ag += rg[c] * xv[c];
      ab += rb[c] * xv[c];
    }
    ag = ag >= 0.f ? ag : 0.1f * ag;
    ab = ab >= 0.f ? ab : 0.1f * ab;
    size_t idx = (size_t)(b * 64 + o) * HW + hw;
    t1g[idx] = ag;
    t1b[idx] = ab;
  }
}

// ---------------------------------------------------------------------------
// SFT stage B: gamma = Wg2 @ t1g, beta = Wb2 @ t1b, out = x*(1+gamma)+beta.
// Same decomposition; xv register column reused for the two input matrices.
// ---------------------------------------------------------------------------
__global__ __launch_bounds__(256) void k_sftB(
    const float* __restrict__ x,
    const float* __restrict__ t1g, const float* __restrict__ t1b,
    const float* __restrict__ wg2, const float* __restrict__ wb2,
    float* __restrict__ out) {
  int tid = threadIdx.x;
  int lane = tid & 63;
  int o_base = __builtin_amdgcn_readfirstlane((tid >> 6) * 16);
  int pg = blockIdx.x * 64 + lane;
  int b = pg >> 14, hw = pg & 16383;

  float xv[64];
  const float* gp = t1g + (size_t)(b * 64) * HW + hw;
#pragma unroll
  for (int c = 0; c < 64; ++c) xv[c] = gp[(size_t)c * HW];

  float g[16];
#pragma unroll 1
  for (int oi = 0; oi < 16; ++oi) {
    const float* rg = wg2 + (size_t)(o_base + oi) * 64;
    float a = 0.f;
#pragma unroll
    for (int c = 0; c < 64; ++c) a += rg[c] * xv[c];
    g[oi] = a;
  }

  const float* bp = t1b + (size_t)(b * 64) * HW + hw;
#pragma unroll
  for (int c = 0; c < 64; ++c) xv[c] = bp[(size_t)c * HW];

  float bt[16];
#pragma unroll 1
  for (int oi = 0; oi < 16; ++oi) {
    const float* rb = wb2 + (size_t)(o_base + oi) * 64;
    float a = 0.f;
#pragma unroll
    for (int c = 0; c < 64; ++c) a += rb[c] * xv[c];
    bt[oi] = a;
  }

#pragma unroll
  for (int oi = 0; oi < 16; ++oi) {
    size_t idx = (size_t)(b * 64 + o_base + oi) * HW + hw;
    float xvv = x[idx];
    out[idx] = xvv + xvv * g[oi] + bt[oi];
  }
}

// ---------------------------------------------------------------------------
// Offset conv, split-K over channels: 4 groups x 256 tiles = 1024 blocks.
// 16x16 px tile, 32 channels/block, register prefetch of next channel's halo
// values (hides global latency behind 243 FMAs), partial sums atomicAdd'ed
// into om_raw (zeroed via memsetAsync). Bias+sigmoid folded into k_dcn.
// ---------------------------------------------------------------------------
__global__ __launch_bounds__(256) void k_conv(
    const float* __restrict__ x, const float* __restrict__ inter,
    const float* __restrict__ w_off, float* __restrict__ om_raw) {
  __shared__ float tile[324];
  int blk = blockIdx.x;
  int g = blk >> 8;                 // channel group 0..3
  int t = blk & 255;
  int b  = t >> 6;
  int h0 = ((t >> 3) & 7) * 16;
  int w0 = (t & 7) * 16;
  int tid = threadIdx.x;
  int ty = tid >> 4, tx = tid & 15;

  // halo slot geometry (each thread stages <=2 of the 324 halo elems)
  int i0 = tid, i1 = tid + 256;
  int r0 = i0 / 18, c0 = i0 % 18;
  int gy0 = h0 - 1 + r0, gx0 = w0 - 1 + c0;
  bool ok0 = ((unsigned)gy0 < 128u) && ((unsigned)gx0 < 128u);
  int ofs0 = gy0 * WW + gx0;
  bool has1 = i1 < 324;
  int r1 = i1 / 18, c1 = i1 % 18;
  int gy1 = h0 - 1 + r1, gx1 = w0 - 1 + c1;
  bool ok1 = has1 && ((unsigned)gy1 < 128u) && ((unsigned)gx1 < 128u);
  int ofs1 = gy1 * WW + gx1;

  const float* src = (g < 2) ? x : inter;
  const float* base = src + (size_t)(b * 64 + (g & 1) * 32) * HW;

  float acc[27];
#pragma unroll
  for (int o = 0; o < 27; ++o) acc[o] = 0.f;

  // prefetch channel 0
  float pv0 = ok0 ? base[ofs0] : 0.f;
  float pv1 = ok1 ? base[ofs1] : 0.f;

  for (int c = 0; c < 32; ++c) {
    __syncthreads();
    tile[i0] = pv0;
    if (has1) tile[i1] = pv1;
    __syncthreads();
    if (c < 31) {
      const float* nb = base + (size_t)(c + 1) * HW;
      pv0 = ok0 ? nb[ofs0] : 0.f;
      pv1 = ok1 ? nb[ofs1] : 0.f;
    }
    float v[9];
#pragma unroll
    for (int r = 0; r < 3; ++r)
#pragma unroll
      for (int cc = 0; cc < 3; ++cc)
        v[r * 3 + cc] = tile[(ty + r) * 18 + tx + cc];
    int cg = g * 32 + c;
#pragma unroll
    for (int o = 0; o < 27; ++o) {
      const float* wr = w_off + (size_t)o * 1152 + (size_t)cg * 9;
#pragma unroll
      for (int tt = 0; tt < 9; ++tt) acc[o] += wr[tt] * v[tt];
    }
  }

  int p = b * HW + (h0 + ty) * WW + (w0 + tx);
#pragma unroll
  for (int j = 0; j < 27; ++j)
    atomicAdd(&om_raw[(size_t)j * NPIX + p], acc[j]);
}

// ---------------------------------------------------------------------------
// NCHW -> channels-last transpose for x (used by DCN gather).
// ---------------------------------------------------------------------------
__global__ __launch_bounds__(256) void k_transpose(
    const float* __restrict__ x, float* __restrict__ x_cl) {
  __shared__ float tile[64 * 129];
  int blk = blockIdx.x;
  int b = blk >> 7, h = blk & 127;
  const float* sp = x + (size_t)(b * CC) * HW + h * WW;
  for (int i = threadIdx.x; i < 64 * 128; i += 256) {
    int c = i >> 7, w = i & 127;
    tile[c * 129 + w] = sp[(size_t)c * HW + w];
  }
  __syncthreads();
  float* dp = x_cl + ((size_t)b * HW + h * WW) * 64;
  for (int i = threadIdx.x; i < 64 * 128; i += 256) {
    int w = i >> 6, c = i & 63;
    dp[w * 64 + c] = tile[c * 129 + w];
  }
}

// ---------------------------------------------------------------------------
// w_dcn [o][c][k] -> wdT [o][k][c]
// ---------------------------------------------------------------------------
__global__ void k_wdt(const float* __restrict__ w_dcn, float* __restrict__ wdT) {
  int i = blockIdx.x * 256 + threadIdx.x;
  if (i < 64 * 64 * 9) {
    int o = i / 576, rem = i % 576, k = rem >> 6, c = rem & 63;
    wdT[i] = w_dcn[(o * 64 + c) * 9 + k];
  }
}

// ---------------------------------------------------------------------------
// DCN. Block = 256 thr (4 waves) = 64 pixels. Bias + sigmoid folded into
// phase 1 (each om_raw element read exactly once across the whole grid).
// ---------------------------------------------------------------------------
__global__ __launch_bounds__(256) void k_dcn(
    const float* __restrict__ x_cl, const float* __restrict__ om_raw,
    const float* __restrict__ b_off, const float* __restrict__ wdT,
    float* __restrict__ out) {
  __shared__ float samp[3 * 64 * 65];
  int tid = threadIdx.x;
  int wave = tid >> 6, lane = tid & 63;
  int pg0 = blockIdx.x * 64;
  int b = pg0 >> 14;
  int o_base = __builtin_amdgcn_readfirstlane(wave * 16);

  float acc[16];
#pragma unroll
  for (int i = 0; i < 16; ++i) acc[i] = 0.f;

  const float* bp = x_cl + (size_t)b * HW * 64;

  for (int k3 = 0; k3 < 3; ++k3) {
    __syncthreads();
    for (int pr = wave; pr < 192; pr += 4) {
      int kk = pr >> 6, p = pr & 63;
      int k = k3 * 3 + kk;
      int pg = pg0 + p;
      int hw = pg & 16383;
      int h = hw >> 7, w = hw & 127;
      float dy = om_raw[(size_t)k * NPIX + pg] + b_off[k];
      float dx = om_raw[(size_t)(9 + k) * NPIX + pg] + b_off[9 + k];
      float mz = om_raw[(size_t)(18 + k) * NPIX + pg] + b_off[18 + k];
      float m = 1.f / (1.f + __expf(-mz));
      float py = (float)(h + (k / 3) - 1) + dy;
      float px = (float)(w + (k % 3) - 1) + dx;
      float y0f = floorf(py), x0f = floorf(px);
      float wy = py - y0f, wx = px - x0f;
      int y0 = (int)y0f, x0 = (int)x0f;
      int c = lane;
      float v00 = 0.f, v01 = 0.f, v10 = 0.f, v11 = 0.f;
      if ((unsigned)y0 < 128u) {
        if ((unsigned)x0 < 128u)       v00 = bp[(size_t)((y0 << 7) + x0) * 64 + c];
        if ((unsigned)(x0 + 1) < 128u) v01 = bp[(size_t)((y0 << 7) + x0 + 1) * 64 + c];
      }
      if ((unsigned)(y0 + 1) < 128u) {
        if ((unsigned)x0 < 128u)       v10 = bp[(size_t)(((y0 + 1) << 7) + x0) * 64 + c];
        if ((unsigned)(x0 + 1) < 128u) v11 = bp[(size_t)(((y0 + 1) << 7) + x0 + 1) * 64 + c];
      }
      float val = v00 * (1.f - wy) * (1.f - wx) + v01 * (1.f - wy) * wx +
                  v10 * wy * (1.f - wx) + v11 * wy * wx;
      samp[(kk * 64 + p) * 65 + c] = m * val;
    }
    __syncthreads();
    for (int kk = 0; kk < 3; ++kk) {
      int k = k3 * 3 + kk;
      const float* wbase = wdT + (size_t)k * 64;
      for (int c0 = 0; c0 < 64; c0 += 16) {
        float sreg[16];
#pragma unroll
        for (int j = 0; j < 16; ++j)
          sreg[j] = samp[(kk * 64 + lane) * 65 + c0 + j];
#pragma unroll
        for (int oi = 0; oi < 16; ++oi) {
          const float* wr = wbase + (size_t)(o_base + oi) * 576 + c0;
#pragma unroll
          for (int j = 0; j < 16; ++j) acc[oi] += wr[j] * sreg[j];
        }
      }
    }
  }

  int hw = (pg0 & 16383) + lane;
#pragma unroll
  for (int oi = 0; oi < 16; ++oi) {
    size_t idx = (size_t)(b * 64 + o_base + oi) * HW + hw;
    out[idx] += acc[oi];
  }
}

// ---------------------------------------------------------------------------
// Workspace plan (floats). Peak concurrent = 8,388,608 floats (33.5 MB).
//   Phase 1 (sftA/sftB):  t1g [0 .. 4194304), t1b [4194304 .. 8388608)
//   Phase 2 (conv..dcn):  x_cl [0 .. 4194304), om_raw [4194304 .. 5963776),
//                         wdT [5963776 .. 6000640)
// t1g/t1b are dead before conv writes om_raw (sftB completes first in-stream).
// ---------------------------------------------------------------------------
extern "C" void kernel_launch(void* const* d_in, const int* in_sizes, int n_in,
                              void* d_out, int out_size, void* d_ws, size_t ws_size,
                              hipStream_t stream) {
  const float* x     = (const float*)d_in[0];
  const float* inter = (const float*)d_in[1];
  const float* w_off = (const float*)d_in[2];
  const float* b_off = (const float*)d_in[3];
  const float* w_dcn = (const float*)d_in[4];
  const float* wg1   = (const float*)d_in[5];
  const float* wg2   = (const float*)d_in[6];
  const float* wb1   = (const float*)d_in[7];
  const float* wb2   = (const float*)d_in[8];
  float* out = (float*)d_out;

  float* ws     = (float*)d_ws;
  float* t1g    = ws;
  float* t1b    = ws + 4194304;
  float* x_cl   = ws;                       // reuses t1g region (t1 dead)
  float* om_raw = ws + 4194304;             // reuses t1b region
  float* wdT    = ws + 4194304 + 1769472;

  // SFT path first (so t1g/t1b can alias x_cl/om_raw).
  k_sftA<<<1024, 256, 0, stream>>>(inter, wg1, wb1, t1g, t1b);
  k_sftB<<<1024, 256, 0, stream>>>(x, t1g, t1b, wg2, wb2, out);

  // Offset conv (split-K, atomic partials).
  hipMemsetAsync(om_raw, 0, (size_t)27 * NPIX * sizeof(float), stream);
  k_conv<<<1024, 256, 0, stream>>>(x, inter, w_off, om_raw);

  // DCN prep + DCN (adds into out).
  k_transpose<<<512, 256, 0, stream>>>(x, x_cl);
  k_wdt<<<144, 256, 0, stream>>>(w_dcn, wdT);
  k_dcn<<<1024, 256, 0, stream>>>(x_cl, om_raw, b_off, wdT, out);
}

// Round 3
// 569.538 us; speedup vs baseline: 2.6089x; 1.2822x over previous
//
#include <hip/hip_runtime.h>
#include <hip/hip_bf16.h>
#include <math.h>

#define BB 4
#define CC 64
#define HH 128
#define WW 128
#define HW (HH*WW)          // 16384
#define NPIX (BB*HW)        // 65536

typedef __attribute__((ext_vector_type(8))) short short8;   // 8 bf16
typedef __attribute__((ext_vector_type(4))) float f32x4;

// ---------------------------------------------------------------------------
// SFT stage A: t1g = lrelu(Wg1 @ inter), t1b = lrelu(Wb1 @ inter).
// ---------------------------------------------------------------------------
__global__ __launch_bounds__(256) void k_sftA(
    const float* __restrict__ inter,
    const float* __restrict__ wg1, const float* __restrict__ wb1,
    float* __restrict__ t1g, float* __restrict__ t1b) {
  int tid = threadIdx.x;
  int lane = tid & 63;
  int o_base = __builtin_amdgcn_readfirstlane((tid >> 6) * 16);
  int pg = blockIdx.x * 64 + lane;
  int b = pg >> 14, hw = pg & 16383;
  const float* ip = inter + (size_t)(b * 64) * HW + hw;

  float xv[64];
#pragma unroll
  for (int c = 0; c < 64; ++c) xv[c] = ip[(size_t)c * HW];

#pragma unroll 1
  for (int oi = 0; oi < 16; ++oi) {
    int o = o_base + oi;
    const float* rg = wg1 + (size_t)o * 64;
    const float* rb = wb1 + (size_t)o * 64;
    float ag = 0.f, ab = 0.f;
#pragma unroll
    for (int c = 0; c < 64; ++c) {
      ag += rg[c] * xv[c];
      ab += rb[c] * xv[c];
    }
    ag = ag >= 0.f ? ag : 0.1f * ag;
    ab = ab >= 0.f ? ab : 0.1f * ab;
    size_t idx = (size_t)(b * 64 + o) * HW + hw;
    t1g[idx] = ag;
    t1b[idx] = ab;
  }
}

// ---------------------------------------------------------------------------
// SFT stage B: gamma = Wg2 @ t1g, beta = Wb2 @ t1b, out = x*(1+gamma)+beta.
// ---------------------------------------------------------------------------
__global__ __launch_bounds__(256) void k_sftB(
    const float* __restrict__ x,
    const float* __restrict__ t1g, const float* __restrict__ t1b,
    const float* __restrict__ wg2, const float* __restrict__ wb2,
    float* __restrict__ out) {
  int tid = threadIdx.x;
  int lane = tid & 63;
  int o_base = __builtin_amdgcn_readfirstlane((tid >> 6) * 16);
  int pg = blockIdx.x * 64 + lane;
  int b = pg >> 14, hw = pg & 16383;

  float xv[64];
  const float* gp = t1g + (size_t)(b * 64) * HW + hw;
#pragma unroll
  for (int c = 0; c < 64; ++c) xv[c] = gp[(size_t)c * HW];

  float g[16];
#pragma unroll 1
  for (int oi = 0; oi < 16; ++oi) {
    const float* rg = wg2 + (size_t)(o_base + oi) * 64;
    float a = 0.f;
#pragma unroll
    for (int c = 0; c < 64; ++c) a += rg[c] * xv[c];
    g[oi] = a;
  }

  const float* bp = t1b + (size_t)(b * 64) * HW + hw;
#pragma unroll
  for (int c = 0; c < 64; ++c) xv[c] = bp[(size_t)c * HW];

  float bt[16];
#pragma unroll 1
  for (int oi = 0; oi < 16; ++oi) {
    const float* rb = wb2 + (size_t)(o_base + oi) * 64;
    float a = 0.f;
#pragma unroll
    for (int c = 0; c < 64; ++c) a += rb[c] * xv[c];
    bt[oi] = a;
  }

#pragma unroll
  for (int oi = 0; oi < 16; ++oi) {
    size_t idx = (size_t)(b * 64 + o_base + oi) * HW + hw;
    float xvv = x[idx];
    out[idx] = xvv + xvv * g[oi] + bt[oi];
  }
}

// ---------------------------------------------------------------------------
// Offset conv, split-K=2 (g=0: x channels, g=1: inter channels), 512 blocks.
// Non-atomic partial sums into om_p[g]; summed in k_dcn's gather (each
// element read exactly once there). Bias+sigmoid also folded into k_dcn.
// ---------------------------------------------------------------------------
__global__ __launch_bounds__(256) void k_conv(
    const float* __restrict__ x, const float* __restrict__ inter,
    const float* __restrict__ w_off,
    float* __restrict__ om_p0, float* __restrict__ om_p1) {
  __shared__ float tile[324];
  int blk = blockIdx.x;
  int g = blk >> 8;                 // 0: x, 1: inter
  int t = blk & 255;
  int b  = t >> 6;
  int h0 = ((t >> 3) & 7) * 16;
  int w0 = (t & 7) * 16;
  int tid = threadIdx.x;
  int ty = tid >> 4, tx = tid & 15;

  int i0 = tid, i1 = tid + 256;
  int r0 = i0 / 18, c0 = i0 % 18;
  int gy0 = h0 - 1 + r0, gx0 = w0 - 1 + c0;
  bool ok0 = ((unsigned)gy0 < 128u) && ((unsigned)gx0 < 128u);
  int ofs0 = gy0 * WW + gx0;
  bool has1 = i1 < 324;
  int r1 = i1 / 18, c1 = i1 % 18;
  int gy1 = h0 - 1 + r1, gx1 = w0 - 1 + c1;
  bool ok1 = has1 && ((unsigned)gy1 < 128u) && ((unsigned)gx1 < 128u);
  int ofs1 = gy1 * WW + gx1;

  const float* src = g ? inter : x;
  const float* base = src + (size_t)(b * 64) * HW;

  float acc[27];
#pragma unroll
  for (int o = 0; o < 27; ++o) acc[o] = 0.f;

  float pv0 = ok0 ? base[ofs0] : 0.f;
  float pv1 = ok1 ? base[ofs1] : 0.f;

  for (int c = 0; c < 64; ++c) {
    __syncthreads();
    tile[i0] = pv0;
    if (has1) tile[i1] = pv1;
    __syncthreads();
    if (c < 63) {
      const float* nb = base + (size_t)(c + 1) * HW;
      pv0 = ok0 ? nb[ofs0] : 0.f;
      pv1 = ok1 ? nb[ofs1] : 0.f;
    }
    float v[9];
#pragma unroll
    for (int r = 0; r < 3; ++r)
#pragma unroll
      for (int cc = 0; cc < 3; ++cc)
        v[r * 3 + cc] = tile[(ty + r) * 18 + tx + cc];
    int cg = g * 64 + c;
#pragma unroll
    for (int o = 0; o < 27; ++o) {
      const float* wr = w_off + (size_t)o * 1152 + (size_t)cg * 9;
#pragma unroll
      for (int tt = 0; tt < 9; ++tt) acc[o] += wr[tt] * v[tt];
    }
  }

  float* dst = g ? om_p1 : om_p0;
  int p = b * HW + (h0 + ty) * WW + (w0 + tx);
#pragma unroll
  for (int j = 0; j < 27; ++j)
    dst[(size_t)j * NPIX + p] = acc[j];
}

// ---------------------------------------------------------------------------
// NCHW -> channels-last transpose for x (DCN gather source).
// ---------------------------------------------------------------------------
__global__ __launch_bounds__(256) void k_transpose(
    const float* __restrict__ x, float* __restrict__ x_cl) {
  __shared__ float tile[64 * 129];
  int blk = blockIdx.x;
  int b = blk >> 7, h = blk & 127;
  const float* sp = x + (size_t)(b * CC) * HW + h * WW;
  for (int i = threadIdx.x; i < 64 * 128; i += 256) {
    int c = i >> 7, w = i & 127;
    tile[c * 129 + w] = sp[(size_t)c * HW + w];
  }
  __syncthreads();
  float* dp = x_cl + ((size_t)b * HW + h * WW) * 64;
  for (int i = threadIdx.x; i < 64 * 128; i += 256) {
    int w = i >> 6, c = i & 63;
    dp[w * 64 + c] = tile[c * 129 + w];
  }
}

// ---------------------------------------------------------------------------
// w_dcn [o][c][k] -> wdT bf16 [o][k*64+c]  (A-operand: k-contiguous rows)
// ---------------------------------------------------------------------------
__global__ void k_wdt(const float* __restrict__ w_dcn, ushort* __restrict__ wdT) {
  int i = blockIdx.x * 256 + threadIdx.x;
  if (i < 64 * 64 * 9) {
    int o = i / 576, rem = i % 576, k = rem >> 6, c = rem & 63;
    __hip_bfloat16 h = __float2bfloat16(w_dcn[(o * 64 + c) * 9 + k]);
    wdT[i] = *(ushort*)&h;
  }
}

// ---------------------------------------------------------------------------
// DCN with MFMA phase 2. Block = 256 thr (4 waves) = 64 pixels.
// 3 chunks of K=192 (3 taps x 64 ch):
//   phase 1: gather bilinear samples (lane=channel, coalesced 256B from
//            x_cl), x mask, convert bf16 -> LDS S[px][klocal], pitch 200.
//   phase 2: D[64o][64px] += W_chunk[64x192] @ S[192x64] via
//            mfma_f32_16x16x32_bf16. Wave w owns o-rows [16w,16w+16):
//            6 ksteps x 4 n-tiles. A-frag from global bf16 wdT (L1-hot).
// Layouts (m89/m91-verified): A[m=lane&15][k=quad*8+j],
// B[k=quad*8+j][n=lane&15], D: col=lane&15, row=quad*4+reg.
// LDS read pattern: pitch 100 dwords == 4 (mod 32) -> minimal 8/bank. 
// ---------------------------------------------------------------------------
#define SPITCH 200   // shorts per pixel row (192 + 8 pad)

__global__ __launch_bounds__(256) void k_dcn(
    const float* __restrict__ x_cl,
    const float* __restrict__ om_p0, const float* __restrict__ om_p1,
    const float* __restrict__ b_off, const ushort* __restrict__ wdT,
    float* __restrict__ out) {
  __shared__ ushort S[64 * SPITCH];   // 25.6 KB
  int tid = threadIdx.x;
  int wave = tid >> 6, lane = tid & 63;
  int quad = lane >> 4, col = lane & 15;
  int pg0 = blockIdx.x * 64;
  int b = pg0 >> 14;
  int o_base = __builtin_amdgcn_readfirstlane(wave * 16);

  f32x4 acc[4];
#pragma unroll
  for (int nt = 0; nt < 4; ++nt) acc[nt] = (f32x4){0.f, 0.f, 0.f, 0.f};

  const float* bp = x_cl + (size_t)b * HW * 64;

  for (int chunk = 0; chunk < 3; ++chunk) {
    __syncthreads();
    // ---- phase 1: gather 192 rows (3 taps x 64 px), lane = channel ----
    for (int pr = wave; pr < 192; pr += 4) {
      int kk = pr >> 6, p = pr & 63;
      int k = chunk * 3 + kk;
      int pg = pg0 + p;
      int hw = pg & 16383;
      int h = hw >> 7, w = hw & 127;
      float dy = om_p0[(size_t)k * NPIX + pg] + om_p1[(size_t)k * NPIX + pg] + b_off[k];
      float dx = om_p0[(size_t)(9 + k) * NPIX + pg] + om_p1[(size_t)(9 + k) * NPIX + pg] + b_off[9 + k];
      float mz = om_p0[(size_t)(18 + k) * NPIX + pg] + om_p1[(size_t)(18 + k) * NPIX + pg] + b_off[18 + k];
      float m = 1.f / (1.f + __expf(-mz));
      float py = (float)(h + (k / 3) - 1) + dy;
      float px = (float)(w + (k % 3) - 1) + dx;
      float y0f = floorf(py), x0f = floorf(px);
      float wy = py - y0f, wx = px - x0f;
      int y0 = (int)y0f, x0 = (int)x0f;
      int c = lane;
      float v00 = 0.f, v01 = 0.f, v10 = 0.f, v11 = 0.f;
      if ((unsigned)y0 < 128u) {
        if ((unsigned)x0 < 128u)       v00 = bp[(size_t)((y0 << 7) + x0) * 64 + c];
        if ((unsigned)(x0 + 1) < 128u) v01 = bp[(size_t)((y0 << 7) + x0 + 1) * 64 + c];
      }
      if ((unsigned)(y0 + 1) < 128u) {
        if ((unsigned)x0 < 128u)       v10 = bp[(size_t)(((y0 + 1) << 7) + x0) * 64 + c];
        if ((unsigned)(x0 + 1) < 128u) v11 = bp[(size_t)(((y0 + 1) << 7) + x0 + 1) * 64 + c];
      }
      float val = v00 * (1.f - wy) * (1.f - wx) + v01 * (1.f - wy) * wx +
                  v10 * wy * (1.f - wx) + v11 * wy * wx;
      val *= m;
      __hip_bfloat16 hv = __float2bfloat16(val);
      S[p * SPITCH + kk * 64 + c] = *(ushort*)&hv;
    }
    __syncthreads();
    // ---- phase 2: MFMA over this chunk's K=192 ----
    const ushort* wrow = wdT + (size_t)(o_base + col) * 576 + chunk * 192 + quad * 8;
    const ushort* srow = S + quad * 8;
#pragma unroll
    for (int ks = 0; ks < 6; ++ks) {
      short8 a = *(const short8*)(wrow + ks * 32);
#pragma unroll
      for (int nt = 0; nt < 4; ++nt) {
        short8 bf = *(const short8*)(srow + (nt * 16 + col) * SPITCH + ks * 32);
        acc[nt] = __builtin_amdgcn_mfma_f32_16x16x32_bf16(a, bf, acc[nt], 0, 0, 0);
      }
    }
  }

  // ---- epilogue: out[(b*64+o)*HW + hw0 + px] += D ----
  int hw0 = pg0 & 16383;
#pragma unroll
  for (int nt = 0; nt < 4; ++nt) {
#pragma unroll
    for (int r = 0; r < 4; ++r) {
      int o = o_base + quad * 4 + r;
      size_t idx = (size_t)(b * 64 + o) * HW + hw0 + nt * 16 + col;
      out[idx] += acc[nt][r];
    }
  }
}

// ---------------------------------------------------------------------------
// Workspace plan (floats). Peak = 8,388,608 floats (33.5 MB) in phase 1;
// phase 2 uses 7.76M floats:
//   x_cl   [0        .. 4194304)
//   om_p0  [4194304  .. 5963776)
//   om_p1  [5963776  .. 7733248)
//   wdT    [7733248  .. 7751680)  (ushort, 36864 elems = 18432 float slots)
// t1g/t1b (phase 1) alias x_cl/om_* and are dead before conv writes.
// ---------------------------------------------------------------------------
extern "C" void kernel_launch(void* const* d_in, const int* in_sizes, int n_in,
                              void* d_out, int out_size, void* d_ws, size_t ws_size,
                              hipStream_t stream) {
  const float* x     = (const float*)d_in[0];
  const float* inter = (const float*)d_in[1];
  const float* w_off = (const float*)d_in[2];
  const float* b_off = (const float*)d_in[3];
  const float* w_dcn = (const float*)d_in[4];
  const float* wg1   = (const float*)d_in[5];
  const float* wg2   = (const float*)d_in[6];
  const float* wb1   = (const float*)d_in[7];
  const float* wb2   = (const float*)d_in[8];
  float* out = (float*)d_out;

  float* ws     = (float*)d_ws;
  float* t1g    = ws;
  float* t1b    = ws + 4194304;
  float* x_cl   = ws;
  float* om_p0  = ws + 4194304;
  float* om_p1  = ws + 5963776;
  ushort* wdT   = (ushort*)(ws + 7733248);

  // SFT path first (t1g/t1b alias phase-2 buffers).
  k_sftA<<<1024, 256, 0, stream>>>(inter, wg1, wb1, t1g, t1b);
  k_sftB<<<1024, 256, 0, stream>>>(x, t1g, t1b, wg2, wb2, out);

  // Offset conv partials (non-atomic).
  k_conv<<<512, 256, 0, stream>>>(x, inter, w_off, om_p0, om_p1);

  // DCN prep + DCN (adds into out).
  k_transpose<<<512, 256, 0, stream>>>(x, x_cl);
  k_wdt<<<144, 256, 0, stream>>>(w_dcn, wdT);
  k_dcn<<<1024, 256, 0, stream>>>(x_cl, om_p0, om_p1, b_off, wdT, out);
}

// Round 4
// 461.933 us; speedup vs baseline: 3.2166x; 1.2329x over previous
//
#include <hip/hip_runtime.h>
#include <hip/hip_bf16.h>
#include <math.h>

#define BB 4
#define CC 64
#define HH 128
#define WW 128
#define HW (HH*WW)          // 16384
#define NPIX (BB*HW)        // 65536

typedef __attribute__((ext_vector_type(8))) short short8;   // 8 bf16
typedef __attribute__((ext_vector_type(4))) float f32x4;

__device__ __forceinline__ float bf2f(ushort u) {
  union { unsigned u; float f; } v; v.u = ((unsigned)u) << 16; return v.f;
}
__device__ __forceinline__ ushort f2bf(float f) {
  __hip_bfloat16 h = __float2bfloat16(f); return *(ushort*)&h;
}

// ---------------------------------------------------------------------------
// SFT stage A: t1g = lrelu(Wg1 @ inter), t1b = lrelu(Wb1 @ inter).
// ---------------------------------------------------------------------------
__global__ __launch_bounds__(256) void k_sftA(
    const float* __restrict__ inter,
    const float* __restrict__ wg1, const float* __restrict__ wb1,
    float* __restrict__ t1g, float* __restrict__ t1b) {
  int tid = threadIdx.x;
  int lane = tid & 63;
  int o_base = __builtin_amdgcn_readfirstlane((tid >> 6) * 16);
  int pg = blockIdx.x * 64 + lane;
  int b = pg >> 14, hw = pg & 16383;
  const float* ip = inter + (size_t)(b * 64) * HW + hw;

  float xv[64];
#pragma unroll
  for (int c = 0; c < 64; ++c) xv[c] = ip[(size_t)c * HW];

#pragma unroll 1
  for (int oi = 0; oi < 16; ++oi) {
    int o = o_base + oi;
    const float* rg = wg1 + (size_t)o * 64;
    const float* rb = wb1 + (size_t)o * 64;
    float ag = 0.f, ab = 0.f;
#pragma unroll
    for (int c = 0; c < 64; ++c) {
      ag += rg[c] * xv[c];
      ab += rb[c] * xv[c];
    }
    ag = ag >= 0.f ? ag : 0.1f * ag;
    ab = ab >= 0.f ? ab : 0.1f * ab;
    size_t idx = (size_t)(b * 64 + o) * HW + hw;
    t1g[idx] = ag;
    t1b[idx] = ab;
  }
}

// ---------------------------------------------------------------------------
// SFT stage B: gamma = Wg2 @ t1g, beta = Wb2 @ t1b, out = x*(1+gamma)+beta.
// ---------------------------------------------------------------------------
__global__ __launch_bounds__(256) void k_sftB(
    const float* __restrict__ x,
    const float* __restrict__ t1g, const float* __restrict__ t1b,
    const float* __restrict__ wg2, const float* __restrict__ wb2,
    float* __restrict__ out) {
  int tid = threadIdx.x;
  int lane = tid & 63;
  int o_base = __builtin_amdgcn_readfirstlane((tid >> 6) * 16);
  int pg = blockIdx.x * 64 + lane;
  int b = pg >> 14, hw = pg & 16383;

  float xv[64];
  const float* gp = t1g + (size_t)(b * 64) * HW + hw;
#pragma unroll
  for (int c = 0; c < 64; ++c) xv[c] = gp[(size_t)c * HW];

  float g[16];
#pragma unroll 1
  for (int oi = 0; oi < 16; ++oi) {
    const float* rg = wg2 + (size_t)(o_base + oi) * 64;
    float a = 0.f;
#pragma unroll
    for (int c = 0; c < 64; ++c) a += rg[c] * xv[c];
    g[oi] = a;
  }

  const float* bp = t1b + (size_t)(b * 64) * HW + hw;
#pragma unroll
  for (int c = 0; c < 64; ++c) xv[c] = bp[(size_t)c * HW];

  float bt[16];
#pragma unroll 1
  for (int oi = 0; oi < 16; ++oi) {
    const float* rb = wb2 + (size_t)(o_base + oi) * 64;
    float a = 0.f;
#pragma unroll
    for (int c = 0; c < 64; ++c) a += rb[c] * xv[c];
    bt[oi] = a;
  }

#pragma unroll
  for (int oi = 0; oi < 16; ++oi) {
    size_t idx = (size_t)(b * 64 + o_base + oi) * HW + hw;
    float xvv = x[idx];
    out[idx] = xvv + xvv * g[oi] + bt[oi];
  }
}

// ---------------------------------------------------------------------------
// NCHW fp32 -> channels-last bf16 for x and inter (1024 blocks: 512 each).
// ---------------------------------------------------------------------------
__global__ __launch_bounds__(256) void k_transp(
    const float* __restrict__ x, const float* __restrict__ inter,
    ushort* __restrict__ x_clh, ushort* __restrict__ inter_clh) {
  __shared__ float tile[64 * 129];
  int blk = blockIdx.x;
  int sel = blk >> 9;
  int bh = blk & 511;
  int b = bh >> 7, h = bh & 127;
  const float* src = sel ? inter : x;
  ushort* dst = sel ? inter_clh : x_clh;
  const float* sp = src + (size_t)(b * 64) * HW + h * WW;
  for (int i = threadIdx.x; i < 64 * 128; i += 256) {
    int c = i >> 7, w = i & 127;
    tile[c * 129 + w] = sp[(size_t)c * HW + w];
  }
  __syncthreads();
  ushort* dp = dst + ((size_t)b * HW + h * WW) * 64;
  for (int i = threadIdx.x; i < 64 * 128; i += 256) {
    int w = i >> 6, c = i & 63;
    dp[w * 64 + c] = f2bf(tile[c * 129 + w]);
  }
}

// ---------------------------------------------------------------------------
// Conv weight prep: wfb[tap][m(32)][c(128)] bf16, m>=27 zero-padded.
// Also zero-fills the 256B zero page used for conv border fragments.
// ---------------------------------------------------------------------------
__global__ void k_wf(const float* __restrict__ w_off, ushort* __restrict__ wfb,
                     float* __restrict__ zp) {
  int i = blockIdx.x * 256 + threadIdx.x;   // 144 blocks -> 36864
  if (i < 64) zp[i] = 0.f;
  if (i < 9 * 32 * 128) {
    int tap = i >> 12, rem = i & 4095, m = rem >> 7, c = rem & 127;
    float v = (m < 27) ? w_off[(size_t)(m * 128 + c) * 9 + tap] : 0.f;
    wfb[i] = f2bf(v);
  }
}

// ---------------------------------------------------------------------------
// w_dcn [o][c][k] -> wdT bf16 [o][k*64+c]  (A-operand rows for DCN MFMA)
// ---------------------------------------------------------------------------
__global__ void k_wdt(const float* __restrict__ w_dcn, ushort* __restrict__ wdT) {
  int i = blockIdx.x * 256 + threadIdx.x;
  if (i < 64 * 64 * 9) {
    int o = i / 576, rem = i % 576, k = rem >> 6, c = rem & 63;
    wdT[i] = f2bf(w_dcn[(o * 64 + c) * 9 + k]);
  }
}

// ---------------------------------------------------------------------------
// Offset conv as implicit GEMM on MFMA. No LDS, no barriers.
// om[27][NPIX] = Wf[27x1152] @ im2col(x++inter), K split as 9 taps x 128 ch.
// Block = 1024 grid: (b, h, half). 4 waves; wave w owns px [half*64+16w, +16),
// m-tiles 0..1 (out 0..15, 16..31; 27..31 dropped at store).
// B-frag: direct 16B global load of 8 consecutive channels at the shifted
// pixel (bf16 channels-last); border lanes select a zero page pointer.
// A-frag: 16B global load from wfb (L1/L2-hot, 72KB total).
// Layouts (m89/m91): A[m=lane&15][k=quad*8+j], B[k][n=lane&15],
// D col=lane&15, row=quad*4+reg.
// ---------------------------------------------------------------------------
__global__ __launch_bounds__(256) void k_convm(
    const ushort* __restrict__ x_clh, const ushort* __restrict__ inter_clh,
    const ushort* __restrict__ wfb, const ushort* __restrict__ zp,
    float* __restrict__ om) {
  int tid = threadIdx.x;
  int wave = tid >> 6, lane = tid & 63;
  int quad = lane >> 4, col = lane & 15;
  int blk = blockIdx.x;                 // b(4) x h(128) x half(2)
  int b = blk >> 8, h = (blk >> 1) & 127, half = blk & 1;
  int px = half * 64 + wave * 16 + col;

  f32x4 acc0 = {0.f, 0.f, 0.f, 0.f}, acc1 = {0.f, 0.f, 0.f, 0.f};

  const ushort* src0 = x_clh + (size_t)b * HW * 64;
  const ushort* src1 = inter_clh + (size_t)b * HW * 64;

#pragma unroll
  for (int ky = 0; ky < 3; ++ky) {
    int hs = h + ky - 1;
    bool hok = (unsigned)hs < 128u;
#pragma unroll
    for (int kx = 0; kx < 3; ++kx) {
      int tap = ky * 3 + kx;
      int ps = px + kx - 1;
      bool ok = hok && ((unsigned)ps < 128u);
      int pofs = ((hs << 7) + ps) * 64 + quad * 8;   // may be junk if !ok
      const ushort* wbase = wfb + (size_t)tap * 4096 + (size_t)col * 128 + quad * 8;
#pragma unroll
      for (int g = 0; g < 2; ++g) {
        const ushort* sb = g ? src1 : src0;
#pragma unroll
        for (int ks = 0; ks < 2; ++ks) {
          const ushort* bp = ok ? (sb + pofs + ks * 32) : zp;
          short8 bfr = *(const short8*)bp;
          short8 a0 = *(const short8*)(wbase + g * 64 + ks * 32);
          short8 a1 = *(const short8*)(wbase + 16 * 128 + g * 64 + ks * 32);
          acc0 = __builtin_amdgcn_mfma_f32_16x16x32_bf16(a0, bfr, acc0, 0, 0, 0);
          acc1 = __builtin_amdgcn_mfma_f32_16x16x32_bf16(a1, bfr, acc1, 0, 0, 0);
        }
      }
    }
  }

  int pg = b * HW + h * WW + px;
#pragma unroll
  for (int r = 0; r < 4; ++r) {
    int o0 = quad * 4 + r;
    om[(size_t)o0 * NPIX + pg] = acc0[r];
    int o1 = 16 + quad * 4 + r;
    if (o1 < 27) om[(size_t)o1 * NPIX + pg] = acc1[r];
  }
}

// ---------------------------------------------------------------------------
// DCN with MFMA phase 2. Block = 256 thr (4 waves) = 64 pixels.
// phase 1: bilinear gather from bf16 channels-last x (lane=channel, 128B
//          coalesced), x mask -> LDS S[px][k] bf16 pitch 200.
// phase 2: D[64o][64px] += W[64x576] @ S via mfma_f32_16x16x32_bf16.
// ---------------------------------------------------------------------------
#define SPITCH 200   // shorts per pixel row (192 + 8 pad)

__global__ __launch_bounds__(256) void k_dcn(
    const ushort* __restrict__ x_clh, const float* __restrict__ om,
    const float* __restrict__ b_off, const ushort* __restrict__ wdT,
    float* __restrict__ out) {
  __shared__ ushort S[64 * SPITCH];   // 25.6 KB
  int tid = threadIdx.x;
  int wave = tid >> 6, lane = tid & 63;
  int quad = lane >> 4, col = lane & 15;
  int pg0 = blockIdx.x * 64;
  int b = pg0 >> 14;
  int o_base = __builtin_amdgcn_readfirstlane(wave * 16);

  f32x4 acc[4];
#pragma unroll
  for (int nt = 0; nt < 4; ++nt) acc[nt] = (f32x4){0.f, 0.f, 0.f, 0.f};

  const ushort* bp = x_clh + (size_t)b * HW * 64;

  for (int chunk = 0; chunk < 3; ++chunk) {
    __syncthreads();
    // ---- phase 1: gather 192 rows (3 taps x 64 px), lane = channel ----
    for (int pr = wave; pr < 192; pr += 4) {
      int kk = pr >> 6, p = pr & 63;
      int k = chunk * 3 + kk;
      int pg = pg0 + p;
      int hw = pg & 16383;
      int h = hw >> 7, w = hw & 127;
      float dy = om[(size_t)k * NPIX + pg] + b_off[k];
      float dx = om[(size_t)(9 + k) * NPIX + pg] + b_off[9 + k];
      float mz = om[(size_t)(18 + k) * NPIX + pg] + b_off[18 + k];
      float m = 1.f / (1.f + __expf(-mz));
      float py = (float)(h + (k / 3) - 1) + dy;
      float px = (float)(w + (k % 3) - 1) + dx;
      float y0f = floorf(py), x0f = floorf(px);
      float wy = py - y0f, wx = px - x0f;
      int y0 = (int)y0f, x0 = (int)x0f;
      int c = lane;
      float v00 = 0.f, v01 = 0.f, v10 = 0.f, v11 = 0.f;
      if ((unsigned)y0 < 128u) {
        if ((unsigned)x0 < 128u)       v00 = bf2f(bp[(size_t)((y0 << 7) + x0) * 64 + c]);
        if ((unsigned)(x0 + 1) < 128u) v01 = bf2f(bp[(size_t)((y0 << 7) + x0 + 1) * 64 + c]);
      }
      if ((unsigned)(y0 + 1) < 128u) {
        if ((unsigned)x0 < 128u)       v10 = bf2f(bp[(size_t)(((y0 + 1) << 7) + x0) * 64 + c]);
        if ((unsigned)(x0 + 1) < 128u) v11 = bf2f(bp[(size_t)(((y0 + 1) << 7) + x0 + 1) * 64 + c]);
      }
      float val = v00 * (1.f - wy) * (1.f - wx) + v01 * (1.f - wy) * wx +
                  v10 * wy * (1.f - wx) + v11 * wy * wx;
      S[p * SPITCH + kk * 64 + c] = f2bf(val * m);
    }
    __syncthreads();
    // ---- phase 2: MFMA over this chunk's K=192 ----
    const ushort* wrow = wdT + (size_t)(o_base + col) * 576 + chunk * 192 + quad * 8;
    const ushort* srow = S + quad * 8;
#pragma unroll
    for (int ks = 0; ks < 6; ++ks) {
      short8 a = *(const short8*)(wrow + ks * 32);
#pragma unroll
      for (int nt = 0; nt < 4; ++nt) {
        short8 bf = *(const short8*)(srow + (nt * 16 + col) * SPITCH + ks * 32);
        acc[nt] = __builtin_amdgcn_mfma_f32_16x16x32_bf16(a, bf, acc[nt], 0, 0, 0);
      }
    }
  }

  // ---- epilogue: out[(b*64+o)*HW + hw0 + px] += D ----
  int hw0 = pg0 & 16383;
#pragma unroll
  for (int nt = 0; nt < 4; ++nt) {
#pragma unroll
    for (int r = 0; r < 4; ++r) {
      int o = o_base + quad * 4 + r;
      size_t idx = (size_t)(b * 64 + o) * HW + hw0 + nt * 16 + col;
      out[idx] += acc[nt][r];
    }
  }
}

// ---------------------------------------------------------------------------
// Workspace plan (float slots). Peak = 8,388,608 floats (33.5 MB):
//   phase 1 (sft):   t1g [0 .. 4194304), t1b [4194304 .. 8388608)
//   phase 2:         x_clh    ushort [0        .. 2097152)   (aliases t1g)
//                    inter_clh ushort [2097152 .. 4194304)   (aliases t1g)
//                    om       fp32   [4194304  .. 5963776)   (aliases t1b)
//                    wfb      ushort [5963776  .. 5982208)
//                    wdT      ushort [5982208  .. 6000640)
//                    zp       fp32   [6000640  .. 6000704)   (zero page)
// Stream order guarantees t1g/t1b are dead before phase-2 writes land.
// ---------------------------------------------------------------------------
extern "C" void kernel_launch(void* const* d_in, const int* in_sizes, int n_in,
                              void* d_out, int out_size, void* d_ws, size_t ws_size,
                              hipStream_t stream) {
  const float* x     = (const float*)d_in[0];
  const float* inter = (const float*)d_in[1];
  const float* w_off = (const float*)d_in[2];
  const float* b_off = (const float*)d_in[3];
  const float* w_dcn = (const float*)d_in[4];
  const float* wg1   = (const float*)d_in[5];
  const float* wg2   = (const float*)d_in[6];
  const float* wb1   = (const float*)d_in[7];
  const float* wb2   = (const float*)d_in[8];
  float* out = (float*)d_out;

  float* ws        = (float*)d_ws;
  float* t1g       = ws;
  float* t1b       = ws + 4194304;
  ushort* x_clh    = (ushort*)ws;
  ushort* inter_clh= (ushort*)(ws + 2097152);
  float* om        = ws + 4194304;
  ushort* wfb      = (ushort*)(ws + 5963776);
  ushort* wdT      = (ushort*)(ws + 5982208);
  float* zp        = ws + 6000640;

  // SFT path first (t1g/t1b alias phase-2 buffers).
  k_sftA<<<1024, 256, 0, stream>>>(inter, wg1, wb1, t1g, t1b);
  k_sftB<<<1024, 256, 0, stream>>>(x, t1g, t1b, wg2, wb2, out);

  // Prep: channels-last bf16 inputs, conv weights, dcn weights, zero page.
  k_transp<<<1024, 256, 0, stream>>>(x, inter, x_clh, inter_clh);
  k_wf<<<144, 256, 0, stream>>>(w_off, wfb, zp);
  k_wdt<<<144, 256, 0, stream>>>(w_dcn, wdT);

  // Offset conv (MFMA implicit GEMM).
  k_convm<<<1024, 256, 0, stream>>>(x_clh, inter_clh, wfb, (const ushort*)zp, om);

  // DCN (adds into out).
  k_dcn<<<1024, 256, 0, stream>>>(x_clh, om, b_off, wdT, out);
}

// Round 5
// 328.179 us; speedup vs baseline: 4.5276x; 1.4076x over previous
//
#include <hip/hip_runtime.h>
#include <hip/hip_bf16.h>
#include <math.h>

#define BB 4
#define CC 64
#define HH 128
#define WW 128
#define HW (HH*WW)          // 16384
#define NPIX (BB*HW)        // 65536

typedef __attribute__((ext_vector_type(8))) short short8;   // 8 bf16
typedef __attribute__((ext_vector_type(4))) float f32x4;

__device__ __forceinline__ float bf2f(ushort u) {
  union { unsigned u; float f; } v; v.u = ((unsigned)u) << 16; return v.f;
}
__device__ __forceinline__ ushort f2bf(float f) {
  __hip_bfloat16 h = __float2bfloat16(f); return *(ushort*)&h;
}

// ---------------------------------------------------------------------------
// SFT stage A: t1g = lrelu(Wg1 @ inter), t1b = lrelu(Wb1 @ inter).
// ---------------------------------------------------------------------------
__global__ __launch_bounds__(256) void k_sftA(
    const float* __restrict__ inter,
    const float* __restrict__ wg1, const float* __restrict__ wb1,
    float* __restrict__ t1g, float* __restrict__ t1b) {
  int tid = threadIdx.x;
  int lane = tid & 63;
  int o_base = __builtin_amdgcn_readfirstlane((tid >> 6) * 16);
  int pg = blockIdx.x * 64 + lane;
  int b = pg >> 14, hw = pg & 16383;
  const float* ip = inter + (size_t)(b * 64) * HW + hw;

  float xv[64];
#pragma unroll
  for (int c = 0; c < 64; ++c) xv[c] = ip[(size_t)c * HW];

#pragma unroll 1
  for (int oi = 0; oi < 16; ++oi) {
    int o = o_base + oi;
    const float* rg = wg1 + (size_t)o * 64;
    const float* rb = wb1 + (size_t)o * 64;
    float ag = 0.f, ab = 0.f;
#pragma unroll
    for (int c = 0; c < 64; ++c) {
      ag += rg[c] * xv[c];
      ab += rb[c] * xv[c];
    }
    ag = ag >= 0.f ? ag : 0.1f * ag;
    ab = ab >= 0.f ? ab : 0.1f * ab;
    size_t idx = (size_t)(b * 64 + o) * HW + hw;
    t1g[idx] = ag;
    t1b[idx] = ab;
  }
}

// ---------------------------------------------------------------------------
// SFT stage B: gamma = Wg2 @ t1g, beta = Wb2 @ t1b, out = x*(1+gamma)+beta.
// ---------------------------------------------------------------------------
__global__ __launch_bounds__(256) void k_sftB(
    const float* __restrict__ x,
    const float* __restrict__ t1g, const float* __restrict__ t1b,
    const float* __restrict__ wg2, const float* __restrict__ wb2,
    float* __restrict__ out) {
  int tid = threadIdx.x;
  int lane = tid & 63;
  int o_base = __builtin_amdgcn_readfirstlane((tid >> 6) * 16);
  int pg = blockIdx.x * 64 + lane;
  int b = pg >> 14, hw = pg & 16383;

  float xv[64];
  const float* gp = t1g + (size_t)(b * 64) * HW + hw;
#pragma unroll
  for (int c = 0; c < 64; ++c) xv[c] = gp[(size_t)c * HW];

  float g[16];
#pragma unroll 1
  for (int oi = 0; oi < 16; ++oi) {
    const float* rg = wg2 + (size_t)(o_base + oi) * 64;
    float a = 0.f;
#pragma unroll
    for (int c = 0; c < 64; ++c) a += rg[c] * xv[c];
    g[oi] = a;
  }

  const float* bp = t1b + (size_t)(b * 64) * HW + hw;
#pragma unroll
  for (int c = 0; c < 64; ++c) xv[c] = bp[(size_t)c * HW];

  float bt[16];
#pragma unroll 1
  for (int oi = 0; oi < 16; ++oi) {
    const float* rb = wb2 + (size_t)(o_base + oi) * 64;
    float a = 0.f;
#pragma unroll
    for (int c = 0; c < 64; ++c) a += rb[c] * xv[c];
    bt[oi] = a;
  }

#pragma unroll
  for (int oi = 0; oi < 16; ++oi) {
    size_t idx = (size_t)(b * 64 + o_base + oi) * HW + hw;
    float xvv = x[idx];
    out[idx] = xvv + xvv * g[oi] + bt[oi];
  }
}

// ---------------------------------------------------------------------------
// NCHW fp32 -> channels-last bf16 for x and inter (1024 blocks: 512 each).
// ---------------------------------------------------------------------------
__global__ __launch_bounds__(256) void k_transp(
    const float* __restrict__ x, const float* __restrict__ inter,
    ushort* __restrict__ x_clh, ushort* __restrict__ inter_clh) {
  __shared__ float tile[64 * 129];
  int blk = blockIdx.x;
  int sel = blk >> 9;
  int bh = blk & 511;
  int b = bh >> 7, h = bh & 127;
  const float* src = sel ? inter : x;
  ushort* dst = sel ? inter_clh : x_clh;
  const float* sp = src + (size_t)(b * 64) * HW + h * WW;
  for (int i = threadIdx.x; i < 64 * 128; i += 256) {
    int c = i >> 7, w = i & 127;
    tile[c * 129 + w] = sp[(size_t)c * HW + w];
  }
  __syncthreads();
  ushort* dp = dst + ((size_t)b * HW + h * WW) * 64;
  for (int i = threadIdx.x; i < 64 * 128; i += 256) {
    int w = i >> 6, c = i & 63;
    dp[w * 64 + c] = f2bf(tile[c * 129 + w]);
  }
}

// ---------------------------------------------------------------------------
// Weight prep (merged): blocks 0..143  -> wfb[tap][m(32)][c(128)] (+zero page)
//                       blocks 144..287-> wdT bf16 [o][k*64+c]
// ---------------------------------------------------------------------------
__global__ void k_wprep(const float* __restrict__ w_off,
                        const float* __restrict__ w_dcn,
                        ushort* __restrict__ wfb, ushort* __restrict__ wdT,
                        float* __restrict__ zp) {
  int blk = blockIdx.x;
  if (blk < 144) {
    int i = blk * 256 + threadIdx.x;
    if (i < 64) zp[i] = 0.f;
    if (i < 9 * 32 * 128) {
      int tap = i >> 12, rem = i & 4095, m = rem >> 7, c = rem & 127;
      float v = (m < 27) ? w_off[(size_t)(m * 128 + c) * 9 + tap] : 0.f;
      wfb[i] = f2bf(v);
    }
  } else {
    int i = (blk - 144) * 256 + threadIdx.x;
    if (i < 64 * 64 * 9) {
      int o = i / 576, rem = i % 576, k = rem >> 6, c = rem & 63;
      wdT[i] = f2bf(w_dcn[(o * 64 + c) * 9 + k]);
    }
  }
}

// ---------------------------------------------------------------------------
// Offset conv as implicit GEMM on MFMA. No LDS, no barriers.
// ---------------------------------------------------------------------------
__global__ __launch_bounds__(256) void k_convm(
    const ushort* __restrict__ x_clh, const ushort* __restrict__ inter_clh,
    const ushort* __restrict__ wfb, const ushort* __restrict__ zp,
    float* __restrict__ om) {
  int tid = threadIdx.x;
  int wave = tid >> 6, lane = tid & 63;
  int quad = lane >> 4, col = lane & 15;
  int blk = blockIdx.x;                 // b(4) x h(128) x half(2)
  int b = blk >> 8, h = (blk >> 1) & 127, half = blk & 1;
  int px = half * 64 + wave * 16 + col;

  f32x4 acc0 = {0.f, 0.f, 0.f, 0.f}, acc1 = {0.f, 0.f, 0.f, 0.f};

  const ushort* src0 = x_clh + (size_t)b * HW * 64;
  const ushort* src1 = inter_clh + (size_t)b * HW * 64;

#pragma unroll
  for (int ky = 0; ky < 3; ++ky) {
    int hs = h + ky - 1;
    bool hok = (unsigned)hs < 128u;
#pragma unroll
    for (int kx = 0; kx < 3; ++kx) {
      int tap = ky * 3 + kx;
      int ps = px + kx - 1;
      bool ok = hok && ((unsigned)ps < 128u);
      int pofs = ((hs << 7) + ps) * 64 + quad * 8;
      const ushort* wbase = wfb + (size_t)tap * 4096 + (size_t)col * 128 + quad * 8;
#pragma unroll
      for (int g = 0; g < 2; ++g) {
        const ushort* sb = g ? src1 : src0;
#pragma unroll
        for (int ks = 0; ks < 2; ++ks) {
          const ushort* bp = ok ? (sb + pofs + ks * 32) : zp;
          short8 bfr = *(const short8*)bp;
          short8 a0 = *(const short8*)(wbase + g * 64 + ks * 32);
          short8 a1 = *(const short8*)(wbase + 16 * 128 + g * 64 + ks * 32);
          acc0 = __builtin_amdgcn_mfma_f32_16x16x32_bf16(a0, bfr, acc0, 0, 0, 0);
          acc1 = __builtin_amdgcn_mfma_f32_16x16x32_bf16(a1, bfr, acc1, 0, 0, 0);
        }
      }
    }
  }

  int pg = b * HW + h * WW + px;
#pragma unroll
  for (int r = 0; r < 4; ++r) {
    int o0 = quad * 4 + r;
    om[(size_t)o0 * NPIX + pg] = acc0[r];
    int o1 = 16 + quad * 4 + r;
    if (o1 < 27) om[(size_t)o1 * NPIX + pg] = acc1[r];
  }
}

// ---------------------------------------------------------------------------
// DCN v2. Block = 256 thr (4 waves) = 32 pixels; 2048 blocks (8/CU).
// Phase 0 (lane=pixel): coalesced om loads, coords/sigmoid computed ONCE per
//   (pixel,tap) -> LDS (y0,x0,wy,wx,m). Kills the 64x-redundant VALU and the
//   same-address om loads of v1.
// Per chunk (3 taps x 64 ch = K=192):
//   phase 1: lane=channel; coords via broadcast LDS read; 4 independent
//            gathers (128B coalesced) -> bilinear -> S[px][k] bf16.
//   phase 2: D[64o][32px] += W chunk @ S via mfma_f32_16x16x32_bf16
//            (wave w: o-rows [16w,16w+16), 6 ksteps x 2 n-tiles).
// LDS 18.6 KB -> 8 blocks/CU; 32 waves/CU to hide L2 gather latency.
// ---------------------------------------------------------------------------
#define SPITCH 200   // shorts per pixel row (192 + 8 pad)
#define NPX 32       // pixels per block

__global__ __launch_bounds__(256) void k_dcn(
    const ushort* __restrict__ x_clh, const float* __restrict__ om,
    const float* __restrict__ b_off, const ushort* __restrict__ wdT,
    float* __restrict__ out) {
  __shared__ ushort S[NPX * SPITCH];       // 12.8 KB
  __shared__ int   cy[9 * NPX], cx[9 * NPX];
  __shared__ float cwy[9 * NPX], cwx[9 * NPX], cm[9 * NPX];

  int tid = threadIdx.x;
  int wave = tid >> 6, lane = tid & 63;
  int quad = lane >> 4, col = lane & 15;
  int pg0 = blockIdx.x * NPX;
  int b = pg0 >> 14;
  int o_base = __builtin_amdgcn_readfirstlane(wave * 16);

  // ---- phase 0: coords once per (pixel, tap), lane = pixel ----
  for (int i = tid; i < 9 * NPX; i += 256) {
    int k = i >> 5, p = i & 31;
    int pg = pg0 + p;
    int hw = pg & 16383;
    int h = hw >> 7, w = hw & 127;
    float dy = om[(size_t)k * NPIX + pg] + b_off[k];
    float dx = om[(size_t)(9 + k) * NPIX + pg] + b_off[9 + k];
    float mz = om[(size_t)(18 + k) * NPIX + pg] + b_off[18 + k];
    float py = (float)(h + (k / 3) - 1) + dy;
    float px = (float)(w + (k % 3) - 1) + dx;
    float y0f = floorf(py), x0f = floorf(px);
    cy[i] = (int)y0f;
    cx[i] = (int)x0f;
    cwy[i] = py - y0f;
    cwx[i] = px - x0f;
    cm[i] = 1.f / (1.f + __expf(-mz));
  }

  f32x4 acc[2];
  acc[0] = (f32x4){0.f, 0.f, 0.f, 0.f};
  acc[1] = (f32x4){0.f, 0.f, 0.f, 0.f};

  const ushort* bp = x_clh + (size_t)b * HW * 64;

  for (int chunk = 0; chunk < 3; ++chunk) {
    __syncthreads();   // chunk 0: coords ready; later: S free for reuse
    // ---- phase 1: gather 96 rows (3 taps x 32 px), lane = channel ----
#pragma unroll 2
    for (int pr = wave; pr < 3 * NPX; pr += 4) {
      int kk = pr >> 5, p = pr & 31;
      int idx = (chunk * 3 + kk) * NPX + p;
      int y0 = cy[idx], x0 = cx[idx];
      float wy = cwy[idx], wx = cwx[idx], m = cm[idx];
      int c = lane;
      float v00 = 0.f, v01 = 0.f, v10 = 0.f, v11 = 0.f;
      if ((unsigned)y0 < 128u) {
        if ((unsigned)x0 < 128u)       v00 = bf2f(bp[(size_t)((y0 << 7) + x0) * 64 + c]);
        if ((unsigned)(x0 + 1) < 128u) v01 = bf2f(bp[(size_t)((y0 << 7) + x0 + 1) * 64 + c]);
      }
      if ((unsigned)(y0 + 1) < 128u) {
        if ((unsigned)x0 < 128u)       v10 = bf2f(bp[(size_t)(((y0 + 1) << 7) + x0) * 64 + c]);
        if ((unsigned)(x0 + 1) < 128u) v11 = bf2f(bp[(size_t)(((y0 + 1) << 7) + x0 + 1) * 64 + c]);
      }
      float top = v00 + (v01 - v00) * wx;
      float bot = v10 + (v11 - v10) * wx;
      float val = top + (bot - top) * wy;
      S[p * SPITCH + kk * 64 + c] = f2bf(val * m);
    }
    __syncthreads();
    // ---- phase 2: MFMA over this chunk's K=192 ----
    const ushort* wrow = wdT + (size_t)(o_base + col) * 576 + chunk * 192 + quad * 8;
    const ushort* srow = S + quad * 8;
#pragma unroll
    for (int ks = 0; ks < 6; ++ks) {
      short8 a = *(const short8*)(wrow + ks * 32);
#pragma unroll
      for (int nt = 0; nt < 2; ++nt) {
        short8 bf = *(const short8*)(srow + (nt * 16 + col) * SPITCH + ks * 32);
        acc[nt] = __builtin_amdgcn_mfma_f32_16x16x32_bf16(a, bf, acc[nt], 0, 0, 0);
      }
    }
  }

  // ---- epilogue: out[(b*64+o)*HW + hw0 + px] += D ----
  int hw0 = pg0 & 16383;
#pragma unroll
  for (int nt = 0; nt < 2; ++nt) {
#pragma unroll
    for (int r = 0; r < 4; ++r) {
      int o = o_base + quad * 4 + r;
      size_t idx = (size_t)(b * 64 + o) * HW + hw0 + nt * 16 + col;
      out[idx] += acc[nt][r];
    }
  }
}

// ---------------------------------------------------------------------------
// Workspace plan (float slots). Peak = 8,388,608 floats (33.5 MB):
//   phase 1 (sft):   t1g [0 .. 4194304), t1b [4194304 .. 8388608)
//   phase 2:         x_clh     ushort [0        .. 2097152)  (aliases t1g)
//                    inter_clh ushort [2097152  .. 4194304)  (aliases t1g)
//                    om        fp32   [4194304  .. 5963776)  (aliases t1b)
//                    wfb       ushort [5963776  .. 5982208)
//                    wdT       ushort [5982208  .. 6000640)
//                    zp        fp32   [6000640  .. 6000704)
// Stream order guarantees t1g/t1b are dead before phase-2 writes land.
// ---------------------------------------------------------------------------
extern "C" void kernel_launch(void* const* d_in, const int* in_sizes, int n_in,
                              void* d_out, int out_size, void* d_ws, size_t ws_size,
                              hipStream_t stream) {
  const float* x     = (const float*)d_in[0];
  const float* inter = (const float*)d_in[1];
  const float* w_off = (const float*)d_in[2];
  const float* b_off = (const float*)d_in[3];
  const float* w_dcn = (const float*)d_in[4];
  const float* wg1   = (const float*)d_in[5];
  const float* wg2   = (const float*)d_in[6];
  const float* wb1   = (const float*)d_in[7];
  const float* wb2   = (const float*)d_in[8];
  float* out = (float*)d_out;

  float* ws        = (float*)d_ws;
  float* t1g       = ws;
  float* t1b       = ws + 4194304;
  ushort* x_clh    = (ushort*)ws;
  ushort* inter_clh= (ushort*)(ws + 2097152);
  float* om        = ws + 4194304;
  ushort* wfb      = (ushort*)(ws + 5963776);
  ushort* wdT      = (ushort*)(ws + 5982208);
  float* zp        = ws + 6000640;

  // SFT path first (t1g/t1b alias phase-2 buffers).
  k_sftA<<<1024, 256, 0, stream>>>(inter, wg1, wb1, t1g, t1b);
  k_sftB<<<1024, 256, 0, stream>>>(x, t1g, t1b, wg2, wb2, out);

  // Prep: channels-last bf16 inputs + weights + zero page.
  k_transp<<<1024, 256, 0, stream>>>(x, inter, x_clh, inter_clh);
  k_wprep<<<288, 256, 0, stream>>>(w_off, w_dcn, wfb, wdT, zp);

  // Offset conv (MFMA implicit GEMM).
  k_convm<<<1024, 256, 0, stream>>>(x_clh, inter_clh, wfb, (const ushort*)zp, om);

  // DCN (adds into out).
  k_dcn<<<2048, 256, 0, stream>>>(x_clh, om, b_off, wdT, out);
}

// Round 6
// 191.308 us; speedup vs baseline: 7.7669x; 1.7155x over previous
//
#include <hip/hip_runtime.h>
#include <hip/hip_bf16.h>
#include <math.h>

#define BB 4
#define CC 64
#define HH 128
#define WW 128
#define HW (HH*WW)          // 16384
#define NPIX (BB*HW)        // 65536

typedef __attribute__((ext_vector_type(8))) short short8;   // 8 bf16
typedef __attribute__((ext_vector_type(4))) float f32x4;

__device__ __forceinline__ float bf2f(ushort u) {
  union { unsigned u; float f; } v; v.u = ((unsigned)u) << 16; return v.f;
}
__device__ __forceinline__ ushort f2bf(float f) {
  __hip_bfloat16 h = __float2bfloat16(f); return *(ushort*)&h;
}

// ---------------------------------------------------------------------------
// NCHW fp32 -> channels-last bf16 for x and inter (1024 blocks: 512 each).
// ---------------------------------------------------------------------------
__global__ __launch_bounds__(256) void k_transp(
    const float* __restrict__ x, const float* __restrict__ inter,
    ushort* __restrict__ x_clh, ushort* __restrict__ inter_clh) {
  __shared__ float tile[64 * 129];
  int blk = blockIdx.x;
  int sel = blk >> 9;
  int bh = blk & 511;
  int b = bh >> 7, h = bh & 127;
  const float* src = sel ? inter : x;
  ushort* dst = sel ? inter_clh : x_clh;
  const float* sp = src + (size_t)(b * 64) * HW + h * WW;
  for (int i = threadIdx.x; i < 64 * 128; i += 256) {
    int c = i >> 7, w = i & 127;
    tile[c * 129 + w] = sp[(size_t)c * HW + w];
  }
  __syncthreads();
  ushort* dp = dst + ((size_t)b * HW + h * WW) * 64;
  for (int i = threadIdx.x; i < 64 * 128; i += 256) {
    int w = i >> 6, c = i & 63;
    dp[w * 64 + c] = f2bf(tile[c * 129 + w]);
  }
}

// ---------------------------------------------------------------------------
// Weight prep: blk 0..143   -> wfb[tap][m(32)][c(128)] (+ zero page)
//              blk 144..287 -> wdT bf16 [o][k*64+c]
//              blk 288..351 -> SFT weight matrices bf16 [o][c]
// ---------------------------------------------------------------------------
__global__ void k_wprep(const float* __restrict__ w_off,
                        const float* __restrict__ w_dcn,
                        const float* __restrict__ wg1, const float* __restrict__ wb1,
                        const float* __restrict__ wg2, const float* __restrict__ wb2,
                        ushort* __restrict__ wfb, ushort* __restrict__ wdT,
                        ushort* __restrict__ w1gb, ushort* __restrict__ w1bb,
                        ushort* __restrict__ w2gb, ushort* __restrict__ w2bb,
                        float* __restrict__ zp) {
  int blk = blockIdx.x;
  if (blk < 144) {
    int i = blk * 256 + threadIdx.x;
    if (i < 64) zp[i] = 0.f;
    if (i < 9 * 32 * 128) {
      int tap = i >> 12, rem = i & 4095, m = rem >> 7, c = rem & 127;
      float v = (m < 27) ? w_off[(size_t)(m * 128 + c) * 9 + tap] : 0.f;
      wfb[i] = f2bf(v);
    }
  } else if (blk < 288) {
    int i = (blk - 144) * 256 + threadIdx.x;
    if (i < 64 * 64 * 9) {
      int o = i / 576, rem = i % 576, k = rem >> 6, c = rem & 63;
      wdT[i] = f2bf(w_dcn[(o * 64 + c) * 9 + k]);
    }
  } else {
    int i = (blk - 288) * 256 + threadIdx.x;   // 0..16383
    int m = i >> 12, j = i & 4095;
    const float* src = (m == 0) ? wg1 : (m == 1) ? wb1 : (m == 2) ? wg2 : wb2;
    ushort* dst = (m == 0) ? w1gb : (m == 1) ? w1bb : (m == 2) ? w2gb : w2bb;
    dst[j] = f2bf(src[j]);
  }
}

// ---------------------------------------------------------------------------
// Fused SFT on MFMA. Block = 256 thr (4 waves) = 64 px; 1024 blocks.
// Stage A: t1{g,b} = lrelu(W1{g,b} @ inter)  — B-frag direct from inter_clh
//          (16B/lane), shared between the two GEMMs.
// LDS: D-layout -> B-layout transform (pitch 72 shorts, 2-way = free).
// Stage B: gamma = W2g @ t1g, beta = W2b @ t1b; out = x*(1+gamma)+beta.
// Layouts (m89/m91): A[m=lane&15][k=quad*8+j], B[k][n=lane&15],
// D col=lane&15 (n), row=quad*4+reg (m).
// ---------------------------------------------------------------------------
#define FPITCH 72   // shorts per px row in Sg/Sb

__global__ __launch_bounds__(256) void k_sft(
    const float* __restrict__ x, const ushort* __restrict__ inter_clh,
    const ushort* __restrict__ w1gb, const ushort* __restrict__ w1bb,
    const ushort* __restrict__ w2gb, const ushort* __restrict__ w2bb,
    float* __restrict__ out) {
  __shared__ ushort Sg[64 * FPITCH];   // 9.2 KB
  __shared__ ushort Sb[64 * FPITCH];   // 9.2 KB
  int tid = threadIdx.x;
  int lane = tid & 63;
  int quad = lane >> 4, col = lane & 15;
  int pg0 = blockIdx.x * 64;
  int b = pg0 >> 14, hw0 = pg0 & 16383;
  int o_base = __builtin_amdgcn_readfirstlane((tid >> 6) * 16);

  // ---- stage A ----
  f32x4 ag[4], ab[4];
#pragma unroll
  for (int nt = 0; nt < 4; ++nt) {
    ag[nt] = (f32x4){0.f, 0.f, 0.f, 0.f};
    ab[nt] = (f32x4){0.f, 0.f, 0.f, 0.f};
  }
#pragma unroll
  for (int ks = 0; ks < 2; ++ks) {
    short8 a_g = *(const short8*)(w1gb + (size_t)(o_base + col) * 64 + ks * 32 + quad * 8);
    short8 a_b = *(const short8*)(w1bb + (size_t)(o_base + col) * 64 + ks * 32 + quad * 8);
#pragma unroll
    for (int nt = 0; nt < 4; ++nt) {
      short8 bf = *(const short8*)(inter_clh + (size_t)(pg0 + nt * 16 + col) * 64 + ks * 32 + quad * 8);
      ag[nt] = __builtin_amdgcn_mfma_f32_16x16x32_bf16(a_g, bf, ag[nt], 0, 0, 0);
      ab[nt] = __builtin_amdgcn_mfma_f32_16x16x32_bf16(a_b, bf, ab[nt], 0, 0, 0);
    }
  }
  // lrelu + D-layout -> LDS [px][o]
#pragma unroll
  for (int nt = 0; nt < 4; ++nt) {
    int px = nt * 16 + col;
    ushort pkg[4], pkb[4];
#pragma unroll
    for (int r = 0; r < 4; ++r) {
      float vg = ag[nt][r]; vg = vg >= 0.f ? vg : 0.1f * vg;
      float vb = ab[nt][r]; vb = vb >= 0.f ? vb : 0.1f * vb;
      pkg[r] = f2bf(vg); pkb[r] = f2bf(vb);
    }
    *(uint2*)(&Sg[px * FPITCH + o_base + quad * 4]) = *(uint2*)pkg;
    *(uint2*)(&Sb[px * FPITCH + o_base + quad * 4]) = *(uint2*)pkb;
  }
  __syncthreads();

  // ---- stage B ----
  f32x4 gg[4], gb[4];
#pragma unroll
  for (int nt = 0; nt < 4; ++nt) {
    gg[nt] = (f32x4){0.f, 0.f, 0.f, 0.f};
    gb[nt] = (f32x4){0.f, 0.f, 0.f, 0.f};
  }
#pragma unroll
  for (int ks = 0; ks < 2; ++ks) {
    short8 a_g = *(const short8*)(w2gb + (size_t)(o_base + col) * 64 + ks * 32 + quad * 8);
    short8 a_b = *(const short8*)(w2bb + (size_t)(o_base + col) * 64 + ks * 32 + quad * 8);
#pragma unroll
    for (int nt = 0; nt < 4; ++nt) {
      short8 bg = *(const short8*)(Sg + (nt * 16 + col) * FPITCH + ks * 32 + quad * 8);
      short8 bb = *(const short8*)(Sb + (nt * 16 + col) * FPITCH + ks * 32 + quad * 8);
      gg[nt] = __builtin_amdgcn_mfma_f32_16x16x32_bf16(a_g, bg, gg[nt], 0, 0, 0);
      gb[nt] = __builtin_amdgcn_mfma_f32_16x16x32_bf16(a_b, bb, gb[nt], 0, 0, 0);
    }
  }

  // ---- epilogue: out = x*(1+gamma) + beta ----
#pragma unroll
  for (int nt = 0; nt < 4; ++nt) {
#pragma unroll
    for (int r = 0; r < 4; ++r) {
      int o = o_base + quad * 4 + r;
      size_t idx = (size_t)(b * 64 + o) * HW + hw0 + nt * 16 + col;
      float xv = x[idx];
      out[idx] = xv + xv * gg[nt][r] + gb[nt][r];
    }
  }
}

// ---------------------------------------------------------------------------
// Offset conv as implicit GEMM on MFMA. No LDS, no barriers.
// ---------------------------------------------------------------------------
__global__ __launch_bounds__(256) void k_convm(
    const ushort* __restrict__ x_clh, const ushort* __restrict__ inter_clh,
    const ushort* __restrict__ wfb, const ushort* __restrict__ zp,
    float* __restrict__ om) {
  int tid = threadIdx.x;
  int wave = tid >> 6, lane = tid & 63;
  int quad = lane >> 4, col = lane & 15;
  int blk = blockIdx.x;                 // b(4) x h(128) x half(2)
  int b = blk >> 8, h = (blk >> 1) & 127, half = blk & 1;
  int px = half * 64 + wave * 16 + col;

  f32x4 acc0 = {0.f, 0.f, 0.f, 0.f}, acc1 = {0.f, 0.f, 0.f, 0.f};

  const ushort* src0 = x_clh + (size_t)b * HW * 64;
  const ushort* src1 = inter_clh + (size_t)b * HW * 64;

#pragma unroll
  for (int ky = 0; ky < 3; ++ky) {
    int hs = h + ky - 1;
    bool hok = (unsigned)hs < 128u;
#pragma unroll
    for (int kx = 0; kx < 3; ++kx) {
      int tap = ky * 3 + kx;
      int ps = px + kx - 1;
      bool ok = hok && ((unsigned)ps < 128u);
      int pofs = ((hs << 7) + ps) * 64 + quad * 8;
      const ushort* wbase = wfb + (size_t)tap * 4096 + (size_t)col * 128 + quad * 8;
#pragma unroll
      for (int g = 0; g < 2; ++g) {
        const ushort* sb = g ? src1 : src0;
#pragma unroll
        for (int ks = 0; ks < 2; ++ks) {
          const ushort* bp = ok ? (sb + pofs + ks * 32) : zp;
          short8 bfr = *(const short8*)bp;
          short8 a0 = *(const short8*)(wbase + g * 64 + ks * 32);
          short8 a1 = *(const short8*)(wbase + 16 * 128 + g * 64 + ks * 32);
          acc0 = __builtin_amdgcn_mfma_f32_16x16x32_bf16(a0, bfr, acc0, 0, 0, 0);
          acc1 = __builtin_amdgcn_mfma_f32_16x16x32_bf16(a1, bfr, acc1, 0, 0, 0);
        }
      }
    }
  }

  int pg = b * HW + h * WW + px;
#pragma unroll
  for (int r = 0; r < 4; ++r) {
    int o0 = quad * 4 + r;
    om[(size_t)o0 * NPIX + pg] = acc0[r];
    int o1 = 16 + quad * 4 + r;
    if (o1 < 27) om[(size_t)o1 * NPIX + pg] = acc1[r];
  }
}

// ---------------------------------------------------------------------------
// DCN v3. Block = 256 thr (4 waves) = 32 pixels; 2048 blocks (8/CU).
// Phase 0: coords once per (pixel,tap) -> LDS (lane=pixel, coalesced om).
// Per chunk (3 taps x 64 ch): phase 1 gathers with lane=(row r, chgroup g):
//   each lane loads 16B (8 ch) per sample point -> 4 dwordx4 loads fetch
//   EIGHT rows per wave-iteration (8x fewer loads / addr-VALU than v2).
//   Interp on 8 channels in registers -> S[px][k] bf16 (bank-uniform write).
// Phase 2: D[64o][32px] += W chunk @ S via mfma_f32_16x16x32_bf16.
// ---------------------------------------------------------------------------
#define SPITCH 200   // shorts per pixel row (192 + 8 pad)
#define NPX 32       // pixels per block

__global__ __launch_bounds__(256) void k_dcn(
    const ushort* __restrict__ x_clh, const float* __restrict__ om,
    const float* __restrict__ b_off, const ushort* __restrict__ wdT,
    const ushort* __restrict__ zp16,
    float* __restrict__ out) {
  __shared__ ushort S[NPX * SPITCH];       // 12.8 KB
  __shared__ int   cy[9 * NPX], cx[9 * NPX];
  __shared__ float cwy[9 * NPX], cwx[9 * NPX], cm[9 * NPX];

  int tid = threadIdx.x;
  int wave = tid >> 6, lane = tid & 63;
  int quad = lane >> 4, col = lane & 15;
  int rr = lane >> 3, g = lane & 7;        // gather: row-in-group, ch-group
  int pg0 = blockIdx.x * NPX;
  int b = pg0 >> 14;
  int o_base = __builtin_amdgcn_readfirstlane(wave * 16);

  // ---- phase 0: coords once per (pixel, tap), lane = pixel ----
  for (int i = tid; i < 9 * NPX; i += 256) {
    int k = i >> 5, p = i & 31;
    int pg = pg0 + p;
    int hw = pg & 16383;
    int h = hw >> 7, w = hw & 127;
    float dy = om[(size_t)k * NPIX + pg] + b_off[k];
    float dx = om[(size_t)(9 + k) * NPIX + pg] + b_off[9 + k];
    float mz = om[(size_t)(18 + k) * NPIX + pg] + b_off[18 + k];
    float py = (float)(h + (k / 3) - 1) + dy;
    float px = (float)(w + (k % 3) - 1) + dx;
    float y0f = floorf(py), x0f = floorf(px);
    cy[i] = (int)y0f;
    cx[i] = (int)x0f;
    cwy[i] = py - y0f;
    cwx[i] = px - x0f;
    cm[i] = 1.f / (1.f + __expf(-mz));
  }

  f32x4 acc[2];
  acc[0] = (f32x4){0.f, 0.f, 0.f, 0.f};
  acc[1] = (f32x4){0.f, 0.f, 0.f, 0.f};

  const ushort* bp = x_clh + (size_t)b * HW * 64;

  for (int chunk = 0; chunk < 3; ++chunk) {
    __syncthreads();   // chunk 0: coords ready; later: S free for reuse
    // ---- phase 1: 96 rows; iteration `it` covers tap kk=it, px p=wave*8+rr
#pragma unroll
    for (int it = 0; it < 3; ++it) {
      int p = wave * 8 + rr;
      int idx = (chunk * 3 + it) * NPX + p;
      int y0 = cy[idx], x0 = cx[idx];
      float wy = cwy[idx], wx = cwx[idx], m = cm[idx];
      bool yok0 = (unsigned)y0 < 128u, yok1 = (unsigned)(y0 + 1) < 128u;
      bool xok0 = (unsigned)x0 < 128u, xok1 = (unsigned)(x0 + 1) < 128u;
      const ushort* r0 = bp + ((size_t)(int)((y0 << 7) + x0)) * 64 + g * 8;
      const ushort* r1 = r0 + (size_t)WW * 64;
      short8 s00 = *(const short8*)((yok0 && xok0) ? r0 : zp16);
      short8 s01 = *(const short8*)((yok0 && xok1) ? (r0 + 64) : zp16);
      short8 s10 = *(const short8*)((yok1 && xok0) ? r1 : zp16);
      short8 s11 = *(const short8*)((yok1 && xok1) ? (r1 + 64) : zp16);
      short8 outv;
#pragma unroll
      for (int j = 0; j < 8; ++j) {
        float v00 = bf2f((ushort)s00[j]), v01 = bf2f((ushort)s01[j]);
        float v10 = bf2f((ushort)s10[j]), v11 = bf2f((ushort)s11[j]);
        float top = v00 + (v01 - v00) * wx;
        float bot = v10 + (v11 - v10) * wx;
        float val = top + (bot - top) * wy;
        outv[j] = (short)f2bf(val * m);
      }
      *(short8*)(&S[p * SPITCH + it * 64 + g * 8]) = outv;
    }
    __syncthreads();
    // ---- phase 2: MFMA over this chunk's K=192 ----
    const ushort* wrow = wdT + (size_t)(o_base + col) * 576 + chunk * 192 + quad * 8;
    const ushort* srow = S + quad * 8;
#pragma unroll
    for (int ks = 0; ks < 6; ++ks) {
      short8 a = *(const short8*)(wrow + ks * 32);
#pragma unroll
      for (int nt = 0; nt < 2; ++nt) {
        short8 bf = *(const short8*)(srow + (nt * 16 + col) * SPITCH + ks * 32);
        acc[nt] = __builtin_amdgcn_mfma_f32_16x16x32_bf16(a, bf, acc[nt], 0, 0, 0);
      }
    }
  }

  // ---- epilogue: out[(b*64+o)*HW + hw0 + px] += D ----
  int hw0 = pg0 & 16383;
#pragma unroll
  for (int nt = 0; nt < 2; ++nt) {
#pragma unroll
    for (int r = 0; r < 4; ++r) {
      int o = o_base + quad * 4 + r;
      size_t idx = (size_t)(b * 64 + o) * HW + hw0 + nt * 16 + col;
      out[idx] += acc[nt][r];
    }
  }
}

// ---------------------------------------------------------------------------
// Workspace plan (float slots), all concurrent (~24 MB):
//   x_clh     ushort [0        .. 2097152)
//   inter_clh ushort [2097152  .. 4194304)
//   om        fp32   [4194304  .. 5963776)
//   wfb       ushort [5963776  .. 5982208)
//   wdT       ushort [5982208  .. 6000640)
//   w1gb/w1bb/w2gb/w2bb ushort 4 x 2048 float slots [6000640 .. 6008832)
//   zp        fp32   [6008832  .. 6008896)
// ---------------------------------------------------------------------------
extern "C" void kernel_launch(void* const* d_in, const int* in_sizes, int n_in,
                              void* d_out, int out_size, void* d_ws, size_t ws_size,
                              hipStream_t stream) {
  const float* x     = (const float*)d_in[0];
  const float* inter = (const float*)d_in[1];
  const float* w_off = (const float*)d_in[2];
  const float* b_off = (const float*)d_in[3];
  const float* w_dcn = (const float*)d_in[4];
  const float* wg1   = (const float*)d_in[5];
  const float* wg2   = (const float*)d_in[6];
  const float* wb1   = (const float*)d_in[7];
  const float* wb2   = (const float*)d_in[8];
  float* out = (float*)d_out;

  float* ws        = (float*)d_ws;
  ushort* x_clh    = (ushort*)ws;
  ushort* inter_clh= (ushort*)(ws + 2097152);
  float* om        = ws + 4194304;
  ushort* wfb      = (ushort*)(ws + 5963776);
  ushort* wdT      = (ushort*)(ws + 5982208);
  ushort* w1gb     = (ushort*)(ws + 6000640);
  ushort* w1bb     = (ushort*)(ws + 6002688);
  ushort* w2gb     = (ushort*)(ws + 6004736);
  ushort* w2bb     = (ushort*)(ws + 6006784);
  float* zp        = ws + 6008832;

  // Prep: channels-last bf16 inputs + all packed weights + zero page.
  k_transp<<<1024, 256, 0, stream>>>(x, inter, x_clh, inter_clh);
  k_wprep<<<352, 256, 0, stream>>>(w_off, w_dcn, wg1, wb1, wg2, wb2,
                                   wfb, wdT, w1gb, w1bb, w2gb, w2bb, zp);

  // SFT (MFMA, fused two stages): out = x*(1+gamma)+beta.
  k_sft<<<1024, 256, 0, stream>>>(x, inter_clh, w1gb, w1bb, w2gb, w2bb, out);

  // Offset conv (MFMA implicit GEMM).
  k_convm<<<1024, 256, 0, stream>>>(x_clh, inter_clh, wfb, (const ushort*)zp, om);

  // DCN (adds into out).
  k_dcn<<<2048, 256, 0, stream>>>(x_clh, om, b_off, wdT, (const ushort*)zp, out);
}

// Round 7
// 183.663 us; speedup vs baseline: 8.0902x; 1.0416x over previous
//
#include <hip/hip_runtime.h>
#include <hip/hip_bf16.h>
#include <math.h>

#define BB 4
#define CC 64
#define HH 128
#define WW 128
#define HW (HH*WW)          // 16384
#define NPIX (BB*HW)        // 65536

typedef __attribute__((ext_vector_type(8))) short short8;   // 8 bf16
typedef __attribute__((ext_vector_type(4))) float f32x4;

__device__ __forceinline__ float bf2f(ushort u) {
  union { unsigned u; float f; } v; v.u = ((unsigned)u) << 16; return v.f;
}
__device__ __forceinline__ ushort f2bf(float f) {
  __hip_bfloat16 h = __float2bfloat16(f); return *(ushort*)&h;
}

// Workspace offsets in ushort units (see plan at bottom).
#define XOFS   0u
#define IOFS   4194304u      // inter_clh
#define ZPOFS  12017664u     // zero page

// ---------------------------------------------------------------------------
// NCHW fp32 -> channels-last bf16 for x and inter (1024 blocks: 512 each).
// ---------------------------------------------------------------------------
__global__ __launch_bounds__(256) void k_transp(
    const float* __restrict__ x, const float* __restrict__ inter,
    ushort* __restrict__ x_clh, ushort* __restrict__ inter_clh) {
  __shared__ float tile[64 * 129];
  int blk = blockIdx.x;
  int sel = blk >> 9;
  int bh = blk & 511;
  int b = bh >> 7, h = bh & 127;
  const float* src = sel ? inter : x;
  ushort* dst = sel ? inter_clh : x_clh;
  const float* sp = src + (size_t)(b * 64) * HW + h * WW;
  for (int i = threadIdx.x; i < 64 * 128; i += 256) {
    int c = i >> 7, w = i & 127;
    tile[c * 129 + w] = sp[(size_t)c * HW + w];
  }
  __syncthreads();
  ushort* dp = dst + ((size_t)b * HW + h * WW) * 64;
  for (int i = threadIdx.x; i < 64 * 128; i += 256) {
    int w = i >> 6, c = i & 63;
    dp[w * 64 + c] = f2bf(tile[c * 129 + w]);
  }
}

// ---------------------------------------------------------------------------
// Weight prep: blk 0..143   -> wfb[tap][m(32)][c(128)] (+ zero page)
//              blk 144..287 -> wdT bf16 [o][k*64+c]
//              blk 288..351 -> SFT weight matrices bf16 [o][c]
// ---------------------------------------------------------------------------
__global__ void k_wprep(const float* __restrict__ w_off,
                        const float* __restrict__ w_dcn,
                        const float* __restrict__ wg1, const float* __restrict__ wb1,
                        const float* __restrict__ wg2, const float* __restrict__ wb2,
                        ushort* __restrict__ wfb, ushort* __restrict__ wdT,
                        ushort* __restrict__ w1gb, ushort* __restrict__ w1bb,
                        ushort* __restrict__ w2gb, ushort* __restrict__ w2bb,
                        float* __restrict__ zp) {
  int blk = blockIdx.x;
  if (blk < 144) {
    int i = blk * 256 + threadIdx.x;
    if (i < 64) zp[i] = 0.f;
    if (i < 9 * 32 * 128) {
      int tap = i >> 12, rem = i & 4095, m = rem >> 7, c = rem & 127;
      float v = (m < 27) ? w_off[(size_t)(m * 128 + c) * 9 + tap] : 0.f;
      wfb[i] = f2bf(v);
    }
  } else if (blk < 288) {
    int i = (blk - 144) * 256 + threadIdx.x;
    if (i < 64 * 64 * 9) {
      int o = i / 576, rem = i % 576, k = rem >> 6, c = rem & 63;
      wdT[i] = f2bf(w_dcn[(o * 64 + c) * 9 + k]);
    }
  } else {
    int i = (blk - 288) * 256 + threadIdx.x;   // 0..16383
    int m = i >> 12, j = i & 4095;
    const float* src = (m == 0) ? wg1 : (m == 1) ? wb1 : (m == 2) ? wg2 : wb2;
    ushort* dst = (m == 0) ? w1gb : (m == 1) ? w1bb : (m == 2) ? w2gb : w2bb;
    dst[j] = f2bf(src[j]);
  }
}

// ---------------------------------------------------------------------------
// Fused SFT on MFMA. Block = 256 thr (4 waves) = 64 px; 1024 blocks.
// ---------------------------------------------------------------------------
#define FPITCH 72   // shorts per px row in Sg/Sb

__global__ __launch_bounds__(256) void k_sft(
    const float* __restrict__ x, const ushort* __restrict__ inter_clh,
    const ushort* __restrict__ w1gb, const ushort* __restrict__ w1bb,
    const ushort* __restrict__ w2gb, const ushort* __restrict__ w2bb,
    float* __restrict__ out) {
  __shared__ ushort Sg[64 * FPITCH];   // 9.2 KB
  __shared__ ushort Sb[64 * FPITCH];   // 9.2 KB
  int tid = threadIdx.x;
  int lane = tid & 63;
  int quad = lane >> 4, col = lane & 15;
  int pg0 = blockIdx.x * 64;
  int b = pg0 >> 14, hw0 = pg0 & 16383;
  int o_base = __builtin_amdgcn_readfirstlane((tid >> 6) * 16);

  // ---- stage A ----
  f32x4 ag[4], ab[4];
#pragma unroll
  for (int nt = 0; nt < 4; ++nt) {
    ag[nt] = (f32x4){0.f, 0.f, 0.f, 0.f};
    ab[nt] = (f32x4){0.f, 0.f, 0.f, 0.f};
  }
#pragma unroll
  for (int ks = 0; ks < 2; ++ks) {
    short8 a_g = *(const short8*)(w1gb + (size_t)(o_base + col) * 64 + ks * 32 + quad * 8);
    short8 a_b = *(const short8*)(w1bb + (size_t)(o_base + col) * 64 + ks * 32 + quad * 8);
#pragma unroll
    for (int nt = 0; nt < 4; ++nt) {
      short8 bf = *(const short8*)(inter_clh + (size_t)(pg0 + nt * 16 + col) * 64 + ks * 32 + quad * 8);
      ag[nt] = __builtin_amdgcn_mfma_f32_16x16x32_bf16(a_g, bf, ag[nt], 0, 0, 0);
      ab[nt] = __builtin_amdgcn_mfma_f32_16x16x32_bf16(a_b, bf, ab[nt], 0, 0, 0);
    }
  }
  // lrelu + D-layout -> LDS [px][o]
#pragma unroll
  for (int nt = 0; nt < 4; ++nt) {
    int px = nt * 16 + col;
    ushort pkg[4], pkb[4];
#pragma unroll
    for (int r = 0; r < 4; ++r) {
      float vg = ag[nt][r]; vg = vg >= 0.f ? vg : 0.1f * vg;
      float vb = ab[nt][r]; vb = vb >= 0.f ? vb : 0.1f * vb;
      pkg[r] = f2bf(vg); pkb[r] = f2bf(vb);
    }
    *(uint2*)(&Sg[px * FPITCH + o_base + quad * 4]) = *(uint2*)pkg;
    *(uint2*)(&Sb[px * FPITCH + o_base + quad * 4]) = *(uint2*)pkb;
  }
  __syncthreads();

  // ---- stage B ----
  f32x4 gg[4], gb[4];
#pragma unroll
  for (int nt = 0; nt < 4; ++nt) {
    gg[nt] = (f32x4){0.f, 0.f, 0.f, 0.f};
    gb[nt] = (f32x4){0.f, 0.f, 0.f, 0.f};
  }
#pragma unroll
  for (int ks = 0; ks < 2; ++ks) {
    short8 a_g = *(const short8*)(w2gb + (size_t)(o_base + col) * 64 + ks * 32 + quad * 8);
    short8 a_b = *(const short8*)(w2bb + (size_t)(o_base + col) * 64 + ks * 32 + quad * 8);
#pragma unroll
    for (int nt = 0; nt < 4; ++nt) {
      short8 bg = *(const short8*)(Sg + (nt * 16 + col) * FPITCH + ks * 32 + quad * 8);
      short8 bb = *(const short8*)(Sb + (nt * 16 + col) * FPITCH + ks * 32 + quad * 8);
      gg[nt] = __builtin_amdgcn_mfma_f32_16x16x32_bf16(a_g, bg, gg[nt], 0, 0, 0);
      gb[nt] = __builtin_amdgcn_mfma_f32_16x16x32_bf16(a_b, bb, gb[nt], 0, 0, 0);
    }
  }

  // ---- epilogue: out = x*(1+gamma) + beta ----
#pragma unroll
  for (int nt = 0; nt < 4; ++nt) {
#pragma unroll
    for (int r = 0; r < 4; ++r) {
      int o = o_base + quad * 4 + r;
      size_t idx = (size_t)(b * 64 + o) * HW + hw0 + nt * 16 + col;
      float xv = x[idx];
      out[idx] = xv + xv * gg[nt][r] + gb[nt][r];
    }
  }
}

// ---------------------------------------------------------------------------
// Offset conv v2: weights-resident implicit GEMM.
// Grid 512 (b x h), block = 4 waves: wave = (px-half, m-tile).
// Per wave: all 36 A-frags (9 taps x 2 src x 2 ksteps) held in 144 VGPRs,
// loaded once. Inner loop per 16-px tile: 9 precomputed 32-bit offsets
// (border -> zero-page offset, all within one workspace slab), then 36
// INDEPENDENT 16B B-loads + 36 MFMAs on two accumulator chains. This gives
// ~36-deep memory ILP per wave (v1 had ~2: VGPR_Count was 40 and each
// iteration serialized on an L2 round trip -> 95% idle).
// ---------------------------------------------------------------------------
__global__ __launch_bounds__(256, 2) void k_convm(
    const ushort* __restrict__ wsb, const ushort* __restrict__ wfb,
    float* __restrict__ om) {
  int tid = threadIdx.x;
  int wave = tid >> 6, lane = tid & 63;
  int quad = lane >> 4, col = lane & 15;
  int blk = blockIdx.x;                 // b(4) x h(128)
  int b = blk >> 7, h = blk & 127;
  int half = wave >> 1, mt = wave & 1;

  // A-frags resident: A[tap][g][ks], m-row = mt*16+col, c = g*64+ks*32+quad*8
  short8 A[36];
  {
    const ushort* wb0 = wfb + (size_t)(mt * 16 + col) * 128 + quad * 8;
#pragma unroll
    for (int tap = 0; tap < 9; ++tap)
#pragma unroll
      for (int g = 0; g < 2; ++g)
#pragma unroll
        for (int ks = 0; ks < 2; ++ks)
          A[tap * 4 + g * 2 + ks] =
              *(const short8*)(wb0 + (size_t)tap * 4096 + g * 64 + ks * 32);
  }

  unsigned bslab = (unsigned)b * HW * 64;
  int pgrow = b * HW + h * WW;

#pragma unroll 1
  for (int t = 0; t < 4; ++t) {
    int px = half * 64 + t * 16 + col;
    // 9 tap offsets (ushort units within workspace slab); border -> zero page
    unsigned ofs[9];
#pragma unroll
    for (int ky = 0; ky < 3; ++ky) {
      int hs = h + ky - 1;
      bool hok = (unsigned)hs < 128u;
#pragma unroll
      for (int kx = 0; kx < 3; ++kx) {
        int ps = px + kx - 1;
        bool ok = hok && ((unsigned)ps < 128u);
        unsigned o = bslab + (unsigned)((hs << 7) + ps) * 64 + quad * 8;
        ofs[ky * 3 + kx] = ok ? o : ZPOFS;
      }
    }
    f32x4 accx = {0.f, 0.f, 0.f, 0.f}, acci = {0.f, 0.f, 0.f, 0.f};
#pragma unroll
    for (int tap = 0; tap < 9; ++tap) {
      const ushort* p = wsb + ofs[tap];
      short8 bx0 = *(const short8*)(p + XOFS);
      short8 bx1 = *(const short8*)(p + XOFS + 32);
      short8 bi0 = *(const short8*)(p + IOFS);
      short8 bi1 = *(const short8*)(p + IOFS + 32);
      accx = __builtin_amdgcn_mfma_f32_16x16x32_bf16(A[tap * 4 + 0], bx0, accx, 0, 0, 0);
      accx = __builtin_amdgcn_mfma_f32_16x16x32_bf16(A[tap * 4 + 1], bx1, accx, 0, 0, 0);
      acci = __builtin_amdgcn_mfma_f32_16x16x32_bf16(A[tap * 4 + 2], bi0, acci, 0, 0, 0);
      acci = __builtin_amdgcn_mfma_f32_16x16x32_bf16(A[tap * 4 + 3], bi1, acci, 0, 0, 0);
    }
    int pg = pgrow + px;
#pragma unroll
    for (int r = 0; r < 4; ++r) {
      int o = mt * 16 + quad * 4 + r;
      float v = accx[r] + acci[r];
      if (o < 27) om[(size_t)o * NPIX + pg] = v;
    }
  }
}

// ---------------------------------------------------------------------------
// DCN v3. Block = 256 thr (4 waves) = 32 pixels; 2048 blocks (8/CU).
// ---------------------------------------------------------------------------
#define SPITCH 200   // shorts per pixel row (192 + 8 pad)
#define NPX 32       // pixels per block

__global__ __launch_bounds__(256) void k_dcn(
    const ushort* __restrict__ x_clh, const float* __restrict__ om,
    const float* __restrict__ b_off, const ushort* __restrict__ wdT,
    const ushort* __restrict__ zp16,
    float* __restrict__ out) {
  __shared__ ushort S[NPX * SPITCH];       // 12.8 KB
  __shared__ int   cy[9 * NPX], cx[9 * NPX];
  __shared__ float cwy[9 * NPX], cwx[9 * NPX], cm[9 * NPX];

  int tid = threadIdx.x;
  int wave = tid >> 6, lane = tid & 63;
  int quad = lane >> 4, col = lane & 15;
  int rr = lane >> 3, g = lane & 7;        // gather: row-in-group, ch-group
  int pg0 = blockIdx.x * NPX;
  int b = pg0 >> 14;
  int o_base = __builtin_amdgcn_readfirstlane(wave * 16);

  // ---- phase 0: coords once per (pixel, tap), lane = pixel ----
  for (int i = tid; i < 9 * NPX; i += 256) {
    int k = i >> 5, p = i & 31;
    int pg = pg0 + p;
    int hw = pg & 16383;
    int h = hw >> 7, w = hw & 127;
    float dy = om[(size_t)k * NPIX + pg] + b_off[k];
    float dx = om[(size_t)(9 + k) * NPIX + pg] + b_off[9 + k];
    float mz = om[(size_t)(18 + k) * NPIX + pg] + b_off[18 + k];
    float py = (float)(h + (k / 3) - 1) + dy;
    float px = (float)(w + (k % 3) - 1) + dx;
    float y0f = floorf(py), x0f = floorf(px);
    cy[i] = (int)y0f;
    cx[i] = (int)x0f;
    cwy[i] = py - y0f;
    cwx[i] = px - x0f;
    cm[i] = 1.f / (1.f + __expf(-mz));
  }

  f32x4 acc[2];
  acc[0] = (f32x4){0.f, 0.f, 0.f, 0.f};
  acc[1] = (f32x4){0.f, 0.f, 0.f, 0.f};

  const ushort* bp = x_clh + (size_t)b * HW * 64;

  for (int chunk = 0; chunk < 3; ++chunk) {
    __syncthreads();   // chunk 0: coords ready; later: S free for reuse
    // ---- phase 1: 96 rows; iteration `it` covers tap kk=it, px p=wave*8+rr
#pragma unroll
    for (int it = 0; it < 3; ++it) {
      int p = wave * 8 + rr;
      int idx = (chunk * 3 + it) * NPX + p;
      int y0 = cy[idx], x0 = cx[idx];
      float wy = cwy[idx], wx = cwx[idx], m = cm[idx];
      bool yok0 = (unsigned)y0 < 128u, yok1 = (unsigned)(y0 + 1) < 128u;
      bool xok0 = (unsigned)x0 < 128u, xok1 = (unsigned)(x0 + 1) < 128u;
      const ushort* r0 = bp + ((size_t)(int)((y0 << 7) + x0)) * 64 + g * 8;
      const ushort* r1 = r0 + (size_t)WW * 64;
      short8 s00 = *(const short8*)((yok0 && xok0) ? r0 : zp16);
      short8 s01 = *(const short8*)((yok0 && xok1) ? (r0 + 64) : zp16);
      short8 s10 = *(const short8*)((yok1 && xok0) ? r1 : zp16);
      short8 s11 = *(const short8*)((yok1 && xok1) ? (r1 + 64) : zp16);
      short8 outv;
#pragma unroll
      for (int j = 0; j < 8; ++j) {
        float v00 = bf2f((ushort)s00[j]), v01 = bf2f((ushort)s01[j]);
        float v10 = bf2f((ushort)s10[j]), v11 = bf2f((ushort)s11[j]);
        float top = v00 + (v01 - v00) * wx;
        float bot = v10 + (v11 - v10) * wx;
        float val = top + (bot - top) * wy;
        outv[j] = (short)f2bf(val * m);
      }
      *(short8*)(&S[p * SPITCH + it * 64 + g * 8]) = outv;
    }
    __syncthreads();
    // ---- phase 2: MFMA over this chunk's K=192 ----
    const ushort* wrow = wdT + (size_t)(o_base + col) * 576 + chunk * 192 + quad * 8;
    const ushort* srow = S + quad * 8;
#pragma unroll
    for (int ks = 0; ks < 6; ++ks) {
      short8 a = *(const short8*)(wrow + ks * 32);
#pragma unroll
      for (int nt = 0; nt < 2; ++nt) {
        short8 bf = *(const short8*)(srow + (nt * 16 + col) * SPITCH + ks * 32);
        acc[nt] = __builtin_amdgcn_mfma_f32_16x16x32_bf16(a, bf, acc[nt], 0, 0, 0);
      }
    }
  }

  // ---- epilogue: out[(b*64+o)*HW + hw0 + px] += D ----
  int hw0 = pg0 & 16383;
#pragma unroll
  for (int nt = 0; nt < 2; ++nt) {
#pragma unroll
    for (int r = 0; r < 4; ++r) {
      int o = o_base + quad * 4 + r;
      size_t idx = (size_t)(b * 64 + o) * HW + hw0 + nt * 16 + col;
      out[idx] += acc[nt][r];
    }
  }
}

// ---------------------------------------------------------------------------
// Workspace plan (float slots), all concurrent (~24 MB):
//   x_clh     ushort [0        .. 2097152)   ushort-ofs 0        (XOFS)
//   inter_clh ushort [2097152  .. 4194304)   ushort-ofs 4194304  (IOFS)
//   om        fp32   [4194304  .. 5963776)
//   wfb       ushort [5963776  .. 5982208)
//   wdT       ushort [5982208  .. 6000640)
//   w1gb/w1bb/w2gb/w2bb ushort 4 x 2048 float slots [6000640 .. 6008832)
//   zp        fp32   [6008832  .. 6008896)   ushort-ofs 12017664 (ZPOFS)
// ---------------------------------------------------------------------------
extern "C" void kernel_launch(void* const* d_in, const int* in_sizes, int n_in,
                              void* d_out, int out_size, void* d_ws, size_t ws_size,
                              hipStream_t stream) {
  const float* x     = (const float*)d_in[0];
  const float* inter = (const float*)d_in[1];
  const float* w_off = (const float*)d_in[2];
  const float* b_off = (const float*)d_in[3];
  const float* w_dcn = (const float*)d_in[4];
  const float* wg1   = (const float*)d_in[5];
  const float* wg2   = (const float*)d_in[6];
  const float* wb1   = (const float*)d_in[7];
  const float* wb2   = (const float*)d_in[8];
  float* out = (float*)d_out;

  float* ws        = (float*)d_ws;
  ushort* wsb      = (ushort*)d_ws;
  ushort* x_clh    = (ushort*)ws;
  ushort* inter_clh= (ushort*)(ws + 2097152);
  float* om        = ws + 4194304;
  ushort* wfb      = (ushort*)(ws + 5963776);
  ushort* wdT      = (ushort*)(ws + 5982208);
  ushort* w1gb     = (ushort*)(ws + 6000640);
  ushort* w1bb     = (ushort*)(ws + 6002688);
  ushort* w2gb     = (ushort*)(ws + 6004736);
  ushort* w2bb     = (ushort*)(ws + 6006784);
  float* zp        = ws + 6008832;

  // Prep: channels-last bf16 inputs + all packed weights + zero page.
  k_transp<<<1024, 256, 0, stream>>>(x, inter, x_clh, inter_clh);
  k_wprep<<<352, 256, 0, stream>>>(w_off, w_dcn, wg1, wb1, wg2, wb2,
                                   wfb, wdT, w1gb, w1bb, w2gb, w2bb, zp);

  // SFT (MFMA, fused two stages): out = x*(1+gamma)+beta.
  k_sft<<<1024, 256, 0, stream>>>(x, inter_clh, w1gb, w1bb, w2gb, w2bb, out);

  // Offset conv (weights-resident MFMA implicit GEMM).
  k_convm<<<512, 256, 0, stream>>>(wsb, wfb, om);

  // DCN (adds into out).
  k_dcn<<<2048, 256, 0, stream>>>(x_clh, om, b_off, wdT, (const ushort*)zp, out);
}